// Round 1
// baseline (42562.234 us; speedup 1.0000x reference)
//
#include <hip/hip_runtime.h>
#include <math.h>

// GraphEncoder: disentangled graph attention, K=2 factors, DK=25, D=50, 4 iters.
// v0: correctness-first. Thread-per-edge + f32 atomics for segment softmax/scatter.
// Segment-max is skipped (vals >= 0 and bounded ~2, exp() safe; softmax identical).

#define KF 2
#define DK 25
#define DD 50
#define ITERS 4

static __device__ __forceinline__ float leakyf(float x) { return x > 0.f ? x : 0.2f * x; }

// P[n][k*25+f] = l2norm_f( leaky( sum_d emb[n][d] * Wtk[k][d][f] ) )
__global__ void fac_kernel(const float* __restrict__ emb, const float* __restrict__ Wtk,
                           int n, float* __restrict__ P) {
    int node = blockIdx.x * blockDim.x + threadIdx.x;
    if (node >= n) return;
    float x[DD];
    const float* er = emb + (size_t)node * DD;
    #pragma unroll
    for (int d = 0; d < DD; ++d) x[d] = er[d];
    float out[DD];
    #pragma unroll
    for (int k = 0; k < KF; ++k) {
        const float* Wk = Wtk + k * DD * DK;  // [50][25]
        float nrm = 0.f;
        for (int f = 0; f < DK; ++f) {
            float acc = 0.f;
            for (int d = 0; d < DD; ++d) acc = fmaf(x[d], Wk[d * DK + f], acc);
            acc = leakyf(acc);
            out[k * DK + f] = acc;
            nrm = fmaf(acc, acc, nrm);
        }
        float inv = 1.f / fmaxf(sqrtf(nrm), 1e-12f);
        for (int f = 0; f < DK; ++f) out[k * DK + f] *= inv;
    }
    float* Pr = P + (size_t)node * DD;
    #pragma unroll
    for (int j = 0; j < DD; ++j) Pr[j] = out[j];
}

// Per edge: logit -> exp -> atomic row sum. ex[e] stored for pass 2.
__global__ void pass1_kernel(const int* __restrict__ rows, const int* __restrict__ cols, int E,
                             const float* __restrict__ Pa, const float* __restrict__ Pb,
                             const float* __restrict__ at_e,  // [2][50]
                             float* __restrict__ ex, float* __restrict__ s) {
    int e = blockIdx.x * blockDim.x + threadIdx.x;
    if (e >= E) return;
    int u = rows[e], c = cols[e];
    const float* pu = Pa + (size_t)u * DD;
    const float* pc = Pb + (size_t)c * DD;
    float d0 = 0.f, d1 = 0.f;
    #pragma unroll
    for (int j = 0; j < DK; ++j) {
        d0 = fmaf(pu[j],      at_e[j],           d0);   // a[0][0..24]  * new factor0
        d1 = fmaf(pu[DK + j], at_e[DD + j],      d1);   // a[1][0..24]  * new factor1
    }
    #pragma unroll
    for (int j = 0; j < DK; ++j) {
        d0 = fmaf(pc[j],      at_e[DK + j],      d0);   // a[0][25..49] * old factor0
        d1 = fmaf(pc[DK + j], at_e[DD + DK + j], d1);   // a[1][25..49] * old factor1
    }
    float v = 0.5f * (fmaxf(d0, 0.f) + fmaxf(d1, 0.f)); // r_node is uniform 1/2 (never updated)
    float ev = expf(v);
    ex[e] = ev;
    atomicAdd(&s[u], ev);
}

// Per edge: attn = ex/s[row]; z[row][:] += attn * Pb[col][:]  (both factors, 50 floats)
__global__ void pass2_kernel(const int* __restrict__ rows, const int* __restrict__ cols, int E,
                             const float* __restrict__ Pb, const float* __restrict__ ex,
                             const float* __restrict__ s, float* __restrict__ z) {
    int e = blockIdx.x * blockDim.x + threadIdx.x;
    if (e >= E) return;
    int u = rows[e], c = cols[e];
    float attn = ex[e] / s[u];
    const float* pc = Pb + (size_t)c * DD;
    float* zr = z + (size_t)u * DD;
    #pragma unroll
    for (int j = 0; j < DD; ++j) atomicAdd(&zr[j], attn * pc[j]);
}

// Per node: z <- leaky(z) @ W ; t_k = sum_f tanh(z_k[f]) q[f] ; r = softmax_k(t)
__global__ void epi_kernel(float* __restrict__ z, const float* __restrict__ W,
                           const float* __restrict__ q, int n, float* __restrict__ r) {
    int node = blockIdx.x * blockDim.x + threadIdx.x;
    if (node >= n) return;
    float zi[DD];
    float* zr = z + (size_t)node * DD;
    #pragma unroll
    for (int j = 0; j < DD; ++j) zi[j] = leakyf(zr[j]);
    float t[KF];
    float out[DD];
    #pragma unroll
    for (int k = 0; k < KF; ++k) {
        float tk = 0.f;
        for (int f = 0; f < DK; ++f) {
            float acc = 0.f;
            for (int d = 0; d < DK; ++d) acc = fmaf(zi[k * DK + d], W[d * DK + f], acc);
            out[k * DK + f] = acc;
            tk = fmaf(tanhf(acc), q[f], tk);
        }
        t[k] = tk;
    }
    float m = fmaxf(t[0], t[1]);
    float e0 = expf(t[0] - m), e1 = expf(t[1] - m);
    float inv = 1.f / (e0 + e1);
    r[(size_t)node * 2 + 0] = e0 * inv;
    r[(size_t)node * 2 + 1] = e1 * inv;
    #pragma unroll
    for (int j = 0; j < DD; ++j) zr[j] = out[j];
}

static __device__ __forceinline__ void l2norm_store(float* dst, const float* acc) {
    #pragma unroll
    for (int k = 0; k < KF; ++k) {
        float nrm = 0.f;
        for (int f = 0; f < DK; ++f) nrm = fmaf(acc[k * DK + f], acc[k * DK + f], nrm);
        float inv = 1.f / fmaxf(sqrtf(nrm), 1e-12f);
        for (int f = 0; f < DK; ++f) dst[k * DK + f] = acc[k * DK + f] * inv;
    }
}

__global__ void ego0_kernel(float* __restrict__ P, const float* __restrict__ z,
                            const float* __restrict__ r, int n) {
    int node = blockIdx.x * blockDim.x + threadIdx.x;
    if (node >= n) return;
    float acc[DD];
    float* Pr = P + (size_t)node * DD;
    const float* zr = z + (size_t)node * DD;
    float r0 = r[(size_t)node * 2], r1 = r[(size_t)node * 2 + 1];
    #pragma unroll
    for (int j = 0; j < DD; ++j) acc[j] = fmaf(zr[j], (j < DK ? r0 : r1), Pr[j]);
    l2norm_store(Pr, acc);
}

struct ZR7 { const float* z[7]; const float* r[7]; };

__global__ void ego1_kernel(float* __restrict__ P, ZR7 p, int n) {
    int node = blockIdx.x * blockDim.x + threadIdx.x;
    if (node >= n) return;
    float acc[DD];
    float* Pr = P + (size_t)node * DD;
    #pragma unroll
    for (int j = 0; j < DD; ++j) acc[j] = Pr[j];
    for (int e = 0; e < 7; ++e) {
        const float* zr = p.z[e] + (size_t)node * DD;
        float r0 = p.r[e][(size_t)node * 2], r1 = p.r[e][(size_t)node * 2 + 1];
        #pragma unroll
        for (int j = 0; j < DD; ++j) acc[j] = fmaf(zr[j], (j < DK ? r0 : r1), acc[j]);
    }
    l2norm_store(Pr, acc);
}

static inline int cdiv(int a, int b) { return (a + b - 1) / b; }

extern "C" void kernel_launch(void* const* d_in, const int* in_sizes, int n_in,
                              void* d_out, int out_size, void* d_ws, size_t ws_size,
                              hipStream_t stream) {
    // ---- inputs ----
    const int* edge[8];
    int E[8];
    for (int e = 0; e < 8; ++e) { edge[e] = (const int*)d_in[e]; E[e] = in_sizes[e] / 2; }
    const float* emb[8];
    int nn[8];
    for (int i = 0; i < 8; ++i) { emb[i] = (const float*)d_in[8 + i]; nn[i] = in_sizes[8 + i] / DD; }
    const float* Wtk = (const float*)d_in[16];  // [8][2][50][25]
    const float* at  = (const float*)d_in[17];  // [8][2][50]
    const float* W   = (const float*)d_in[18];  // [25][25]
    const float* q   = (const float*)d_in[19];  // [8][25]
    float* out = (float*)d_out;

    static const int aIdx[8] = {0, 1, 1, 1, 1, 1, 1, 1};
    static const int bIdx[8] = {1, 0, 2, 3, 4, 5, 6, 7};
    int rows[8];
    for (int e = 0; e < 8; ++e) rows[e] = nn[aIdx[e]];

    // ---- workspace layout (floats) ----
    float* w = (float*)d_ws;
    size_t off = 0;
    float* P[8];
    for (int i = 0; i < 8; ++i) { P[i] = w + off; off += (size_t)nn[i] * DD; }
    float* z[8];
    for (int e = 0; e < 8; ++e) { z[e] = w + off; off += (size_t)rows[e] * DD; }
    float* r[8];
    for (int e = 0; e < 8; ++e) { r[e] = w + off; off += (size_t)rows[e] * 2; }
    int maxE = 0, maxRows = 0;
    for (int e = 0; e < 8; ++e) { if (E[e] > maxE) maxE = E[e]; if (rows[e] > maxRows) maxRows = rows[e]; }
    float* ex = w + off; off += (size_t)maxE;
    float* s  = w + off; off += (size_t)maxRows;

    const int B = 256;

    // ---- fac: project all 8 node types ----
    for (int i = 0; i < 8; ++i)
        fac_kernel<<<cdiv(nn[i], B), B, 0, stream>>>(emb[i], Wtk + (size_t)i * KF * DD * DK, nn[i], P[i]);

    // ---- 4 message-passing iterations ----
    for (int it = 0; it < ITERS; ++it) {
        for (int e = 0; e < 8; ++e) {
            hipMemsetAsync(s, 0, (size_t)rows[e] * sizeof(float), stream);
            hipMemsetAsync(z[e], 0, (size_t)rows[e] * DD * sizeof(float), stream);
            pass1_kernel<<<cdiv(E[e], B), B, 0, stream>>>(
                edge[e], edge[e] + E[e], E[e], P[aIdx[e]], P[bIdx[e]],
                at + (size_t)e * KF * DD, ex, s);
            pass2_kernel<<<cdiv(E[e], B), B, 0, stream>>>(
                edge[e], edge[e] + E[e], E[e], P[bIdx[e]], ex, s, z[e]);
            epi_kernel<<<cdiv(rows[e], B), B, 0, stream>>>(
                z[e], W, q + (size_t)e * DK, rows[e], r[e]);
        }
        ego0_kernel<<<cdiv(nn[0], B), B, 0, stream>>>(P[0], z[0], r[0], nn[0]);
        ZR7 p;
        for (int e = 0; e < 7; ++e) { p.z[e] = z[e + 1]; p.r[e] = r[e + 1]; }
        ego1_kernel<<<cdiv(nn[1], B), B, 0, stream>>>(P[1], p, nn[1]);
    }

    // ---- output: concat(flat(P0), flat(P1)) — node-major layout already matches ----
    hipMemcpyAsync(out, P[0], (size_t)nn[0] * DD * sizeof(float), hipMemcpyDeviceToDevice, stream);
    hipMemcpyAsync(out + (size_t)nn[0] * DD, P[1], (size_t)nn[1] * DD * sizeof(float),
                   hipMemcpyDeviceToDevice, stream);
}

// Round 2
// 3434.554 us; speedup vs baseline: 12.3924x; 12.3924x over previous
//
#include <hip/hip_runtime.h>
#include <math.h>

// GraphEncoder v1: CSR + wave-per-row fused attention (zero atomics in hot path).
// Softmax normalizer is linear -> single pass per row:
//   z[u] = (sum_e ev_e * Pb[col_e]) / (sum_e ev_e)
// Epilogue (leaky -> @W -> tanh*q -> factor softmax) fused via __shfl transpose.
// CSR built on-device each call (hist -> block scan -> scatter).

#define KF 2
#define DK 25
#define DD 50
#define ITERS 4
#define WPB 4   // waves per block in phase kernel

static __device__ __forceinline__ float leakyf(float x) { return x > 0.f ? x : 0.2f * x; }

// ---------------- fac: P[n][k*25+f] = l2norm_f(leaky(emb @ Wtk)) ----------------
struct FacArgs { const float* emb[8]; float* P[8]; const float* Wtk; int base[9]; };

__global__ void fac_kernel(FacArgs A) {
    int g = blockIdx.x * blockDim.x + threadIdx.x;
    if (g >= A.base[8]) return;
    int ty = 0;
    while (g >= A.base[ty + 1]) ++ty;
    int node = g - A.base[ty];
    const float* er = A.emb[ty] + (size_t)node * DD;
    const float* Wt = A.Wtk + (size_t)ty * KF * DD * DK;
    float x[DD];
    #pragma unroll
    for (int d = 0; d < DD; ++d) x[d] = er[d];
    float out[DD];
    #pragma unroll
    for (int k = 0; k < KF; ++k) {
        const float* Wk = Wt + k * DD * DK;
        float nrm = 0.f;
        for (int f = 0; f < DK; ++f) {
            float acc = 0.f;
            for (int d = 0; d < DD; ++d) acc = fmaf(x[d], Wk[d * DK + f], acc);
            acc = leakyf(acc);
            out[k * DK + f] = acc;
            nrm = fmaf(acc, acc, nrm);
        }
        float inv = 1.f / fmaxf(sqrtf(nrm), 1e-12f);
        for (int f = 0; f < DK; ++f) out[k * DK + f] *= inv;
    }
    float* Pr = A.P[ty] + (size_t)node * DD;
    #pragma unroll
    for (int j = 0; j < DD; ++j) Pr[j] = out[j];
}

// ---------------- CSR build ----------------
struct EdgeArgs {
    const int* rows[8]; const int* cols[8];
    int* cnt[8];      // also becomes rowptr after in-place scan
    int* cur[8];
    int* colind[8];
    int ebase[9];
};

__global__ void hist_kernel(EdgeArgs A) {
    int g = blockIdx.x * blockDim.x + threadIdx.x;
    if (g >= A.ebase[8]) return;
    int rel = 0;
    while (g >= A.ebase[rel + 1]) ++rel;
    int e = g - A.ebase[rel];
    atomicAdd(&A.cnt[rel][A.rows[rel][e]], 1);
}

struct ScanArgs { int* a[8]; int n[8]; };

// one block per relation; in-place exclusive scan of a[0..n), a[n] = total
__global__ __launch_bounds__(1024) void scan_kernel(ScanArgs A) {
    __shared__ int lds[1024];
    __shared__ int s_carry;
    int* a = A.a[blockIdx.x];
    int n = A.n[blockIdx.x];
    int tid = threadIdx.x;
    if (tid == 0) s_carry = 0;
    __syncthreads();
    for (int base = 0; base < n; base += 1024) {
        int i = base + tid;
        int v = (i < n) ? a[i] : 0;
        lds[tid] = v;
        __syncthreads();
        int x = v;
        for (int off = 1; off < 1024; off <<= 1) {
            int y = (tid >= off) ? lds[tid - off] : 0;
            __syncthreads();
            x += y;
            lds[tid] = x;
            __syncthreads();
        }
        int total = lds[1023];
        int carry = s_carry;
        if (i < n) a[i] = carry + x - v;   // exclusive
        __syncthreads();
        if (tid == 0) s_carry = carry + total;
        __syncthreads();
    }
    if (tid == 0) a[n] = s_carry;
}

__global__ void scatter_kernel(EdgeArgs A) {
    int g = blockIdx.x * blockDim.x + threadIdx.x;
    if (g >= A.ebase[8]) return;
    int rel = 0;
    while (g >= A.ebase[rel + 1]) ++rel;
    int e = g - A.ebase[rel];
    int row = A.rows[rel][e];
    int p = atomicAdd(&A.cur[rel][row], 1);
    A.colind[rel][p] = A.cols[rel][e];
}

// ---------------- fused phase: attention-aggregate + epilogue, all 8 relations ----------------
struct PhaseArgs {
    const int* rowptr[8]; const int* colind[8];
    const float* Pa[8]; const float* Pb[8];
    const float* at[8]; const float* q[8];
    float* z[8]; float* r[8];
    const float* W;
    int rowbase[9];
};

__global__ __launch_bounds__(WPB * 64) void phase_kernel(PhaseArgs A, int totalRows) {
    int wave = blockIdx.x * WPB + (threadIdx.x >> 6);
    int lane = threadIdx.x & 63;
    if (wave >= totalRows) return;
    int rel = 0;
    while (wave >= A.rowbase[rel + 1]) ++rel;
    int u = wave - A.rowbase[rel];

    const int* rowptr = A.rowptr[rel];
    const int* colind = A.colind[rel];
    const float* Pa = A.Pa[rel];
    const float* Pb = A.Pb[rel];
    const float* at_e = A.at[rel];   // [2][50]
    const float* qv = A.q[rel];      // [25]
    int beg = rowptr[u], end = rowptr[u + 1];

    bool act = lane < DD;
    // row-constant half of the logit: h_k = sum_f pu[k*25+f] * a_k[f]
    float puj  = act ? Pa[(size_t)u * DD + lane] : 0.f;
    float anew = act ? ((lane < DK) ? at_e[lane] : at_e[DD + (lane - DK)]) : 0.f;
    float v0 = (lane < DK) ? puj * anew : 0.f;
    float v1 = puj * anew - v0;
    #pragma unroll
    for (int off = 32; off; off >>= 1) { v0 += __shfl_xor(v0, off); v1 += __shfl_xor(v1, off); }
    float h0 = v0, h1 = v1;
    // per-edge coefficient: d_k += pc[k*25+f] * a_k[25+f]
    float aold = act ? ((lane < DK) ? at_e[DK + lane] : at_e[DD + lane]) : 0.f;

    float ssum = 0.f, acc = 0.f;
    for (int base = beg; base < end; base += 64) {
        int cb = (base + lane < end) ? colind[base + lane] : 0;
        int nb = min(64, end - base);
        for (int t = 0; t < nb; ++t) {
            int c = __shfl(cb, t);
            float pcj = act ? Pb[(size_t)c * DD + lane] : 0.f;
            float wall = pcj * aold;
            float w0 = (lane < DK) ? wall : 0.f;
            float w1 = wall - w0;
            #pragma unroll
            for (int off = 32; off; off >>= 1) { w0 += __shfl_xor(w0, off); w1 += __shfl_xor(w1, off); }
            float ev = __expf(0.5f * (fmaxf(h0 + w0, 0.f) + fmaxf(h1 + w1, 0.f)));
            ssum += ev;
            acc = fmaf(ev, pcj, acc);
        }
    }
    float inv = (ssum > 0.f) ? (1.f / ssum) : 0.f;
    float zl = leakyf(acc * inv);   // leaky(z_agg), lane-distributed

    // o = z @ W per factor, via shfl transpose
    int fcol = act ? ((lane < DK) ? lane : (lane - DK)) : 0;
    int kbase = (act && lane >= DK) ? DK : 0;
    float o = 0.f;
    const float* W = A.W;
    #pragma unroll
    for (int d = 0; d < DK; ++d) {
        float zd = __shfl(zl, kbase + d);
        o = fmaf(zd, W[d * DK + fcol], o);
    }
    // t_k = sum_f tanh(o_kf) * q[f]; r = softmax over k
    float th = act ? tanhf(o) * qv[fcol] : 0.f;
    float t0 = (lane < DK) ? th : 0.f;
    float t1 = th - t0;
    #pragma unroll
    for (int off = 32; off; off >>= 1) { t0 += __shfl_xor(t0, off); t1 += __shfl_xor(t1, off); }
    float m = fmaxf(t0, t1);
    float e0 = __expf(t0 - m), e1 = __expf(t1 - m);
    float rinv = 1.f / (e0 + e1);

    if (act) A.z[rel][(size_t)u * DD + lane] = o;
    if (lane == 0) {
        A.r[rel][(size_t)u * 2 + 0] = e0 * rinv;
        A.r[rel][(size_t)u * 2 + 1] = e1 * rinv;
    }
}

// ---------------- ego update: both node types in one launch ----------------
static __device__ __forceinline__ void l2norm_store(float* dst, const float* acc) {
    #pragma unroll
    for (int k = 0; k < KF; ++k) {
        float nrm = 0.f;
        for (int f = 0; f < DK; ++f) nrm = fmaf(acc[k * DK + f], acc[k * DK + f], nrm);
        float inv = 1.f / fmaxf(sqrtf(nrm), 1e-12f);
        for (int f = 0; f < DK; ++f) dst[k * DK + f] = acc[k * DK + f] * inv;
    }
}

struct EgoArgs { float* P0; float* P1; const float* zz[8]; const float* rr[8]; int n0, n1; };

__global__ void ego_kernel(EgoArgs A) {
    int g = blockIdx.x * blockDim.x + threadIdx.x;
    if (g >= A.n0 + A.n1) return;
    float acc[DD];
    if (g < A.n0) {
        float* Pr = A.P0 + (size_t)g * DD;
        const float* zr = A.zz[0] + (size_t)g * DD;
        float r0 = A.rr[0][(size_t)g * 2], r1 = A.rr[0][(size_t)g * 2 + 1];
        #pragma unroll
        for (int j = 0; j < DD; ++j) acc[j] = fmaf(zr[j], (j < DK ? r0 : r1), Pr[j]);
        l2norm_store(Pr, acc);
    } else {
        int node = g - A.n0;
        float* Pr = A.P1 + (size_t)node * DD;
        #pragma unroll
        for (int j = 0; j < DD; ++j) acc[j] = Pr[j];
        for (int e = 1; e < 8; ++e) {
            const float* zr = A.zz[e] + (size_t)node * DD;
            float r0 = A.rr[e][(size_t)node * 2], r1 = A.rr[e][(size_t)node * 2 + 1];
            #pragma unroll
            for (int j = 0; j < DD; ++j) acc[j] = fmaf(zr[j], (j < DK ? r0 : r1), acc[j]);
        }
        l2norm_store(Pr, acc);
    }
}

static inline int cdiv(int a, int b) { return (a + b - 1) / b; }

extern "C" void kernel_launch(void* const* d_in, const int* in_sizes, int n_in,
                              void* d_out, int out_size, void* d_ws, size_t ws_size,
                              hipStream_t stream) {
    // ---- inputs ----
    const int* edge[8];
    int E[8];
    for (int e = 0; e < 8; ++e) { edge[e] = (const int*)d_in[e]; E[e] = in_sizes[e] / 2; }
    const float* emb[8];
    int nn[8];
    for (int i = 0; i < 8; ++i) { emb[i] = (const float*)d_in[8 + i]; nn[i] = in_sizes[8 + i] / DD; }
    const float* Wtk = (const float*)d_in[16];
    const float* at  = (const float*)d_in[17];
    const float* W   = (const float*)d_in[18];
    const float* q   = (const float*)d_in[19];
    float* out = (float*)d_out;

    static const int aIdx[8] = {0, 1, 1, 1, 1, 1, 1, 1};
    static const int bIdx[8] = {1, 0, 2, 3, 4, 5, 6, 7};
    int rows[8];
    for (int e = 0; e < 8; ++e) rows[e] = nn[aIdx[e]];

    // ---- workspace layout ----
    char* w = (char*)d_ws;
    size_t off = 0;
    auto alloc_f = [&](size_t n) { float* p = (float*)(w + off); off += n * 4; return p; };
    auto alloc_i = [&](size_t n) { int* p = (int*)(w + off); off += n * 4; return p; };
    float* P[8]; for (int i = 0; i < 8; ++i) P[i] = alloc_f((size_t)nn[i] * DD);
    float* z[8]; for (int e = 0; e < 8; ++e) z[e] = alloc_f((size_t)rows[e] * DD);
    float* r[8]; for (int e = 0; e < 8; ++e) r[e] = alloc_f((size_t)rows[e] * 2);
    int* cntrp_all = alloc_i(0);  // marker
    int* cntrp[8]; for (int e = 0; e < 8; ++e) cntrp[e] = alloc_i((size_t)rows[e] + 1);
    size_t cnt_total = 0; for (int e = 0; e < 8; ++e) cnt_total += rows[e] + 1;
    int* cur_all = alloc_i(0);
    int* cur[8]; for (int e = 0; e < 8; ++e) cur[e] = alloc_i((size_t)rows[e] + 1);
    int* colind[8]; for (int e = 0; e < 8; ++e) colind[e] = alloc_i((size_t)E[e]);

    const int B = 256;

    // ---- CSR build (once per call) ----
    hipMemsetAsync(cntrp_all, 0, cnt_total * 4, stream);
    EdgeArgs EA;
    EA.ebase[0] = 0;
    for (int e = 0; e < 8; ++e) {
        EA.rows[e] = edge[e]; EA.cols[e] = edge[e] + E[e];
        EA.cnt[e] = cntrp[e]; EA.cur[e] = cur[e]; EA.colind[e] = colind[e];
        EA.ebase[e + 1] = EA.ebase[e] + E[e];
    }
    int totE = EA.ebase[8];
    hist_kernel<<<cdiv(totE, B), B, 0, stream>>>(EA);
    ScanArgs SA;
    for (int e = 0; e < 8; ++e) { SA.a[e] = cntrp[e]; SA.n[e] = rows[e]; }
    scan_kernel<<<8, 1024, 0, stream>>>(SA);
    hipMemcpyAsync(cur_all, cntrp_all, cnt_total * 4, hipMemcpyDeviceToDevice, stream);
    scatter_kernel<<<cdiv(totE, B), B, 0, stream>>>(EA);

    // ---- fac ----
    FacArgs FA;
    FA.base[0] = 0;
    for (int i = 0; i < 8; ++i) { FA.emb[i] = emb[i]; FA.P[i] = P[i]; FA.base[i + 1] = FA.base[i] + nn[i]; }
    FA.Wtk = Wtk;
    fac_kernel<<<cdiv(FA.base[8], B), B, 0, stream>>>(FA);

    // ---- iterations ----
    PhaseArgs PA;
    PA.rowbase[0] = 0;
    for (int e = 0; e < 8; ++e) {
        PA.rowptr[e] = cntrp[e]; PA.colind[e] = colind[e];
        PA.Pa[e] = P[aIdx[e]];   PA.Pb[e] = P[bIdx[e]];
        PA.at[e] = at + (size_t)e * KF * DD;
        PA.q[e]  = q + (size_t)e * DK;
        PA.z[e] = z[e]; PA.r[e] = r[e];
        PA.rowbase[e + 1] = PA.rowbase[e] + rows[e];
    }
    PA.W = W;
    int totalRows = PA.rowbase[8];
    EgoArgs GA;
    GA.P0 = P[0]; GA.P1 = P[1]; GA.n0 = nn[0]; GA.n1 = nn[1];
    for (int e = 0; e < 8; ++e) { GA.zz[e] = z[e]; GA.rr[e] = r[e]; }

    for (int it = 0; it < ITERS; ++it) {
        phase_kernel<<<cdiv(totalRows, WPB), WPB * 64, 0, stream>>>(PA, totalRows);
        ego_kernel<<<cdiv(nn[0] + nn[1], B), B, 0, stream>>>(GA);
    }

    // ---- output ----
    hipMemcpyAsync(out, P[0], (size_t)nn[0] * DD * 4, hipMemcpyDeviceToDevice, stream);
    hipMemcpyAsync(out + (size_t)nn[0] * DD, P[1], (size_t)nn[1] * DD * 4,
                   hipMemcpyDeviceToDevice, stream);
}

// Round 4
// 2313.575 us; speedup vs baseline: 18.3967x; 1.4845x over previous
//
#include <hip/hip_runtime.h>
#include <math.h>

// GraphEncoder v2.1: v2 with the readlane float-truncation bug fixed.
// (__builtin_amdgcn_readlane is int-typed; floats must be bit-cast, not
// value-converted. v2 truncated exp() weights to integers.)

#define KF 2
#define DK 25
#define DD 50
#define ITERS 4
#define WPB 4

static __device__ __forceinline__ float leakyf(float x) { return x > 0.f ? x : 0.2f * x; }

// ---------------- fac ----------------
struct FacArgs { const float* emb[8]; float* P[8]; const float* Wtk; int base[9]; };

__global__ void fac_kernel(FacArgs A) {
    int g = blockIdx.x * blockDim.x + threadIdx.x;
    if (g >= A.base[8]) return;
    int ty = 0;
    while (g >= A.base[ty + 1]) ++ty;
    int node = g - A.base[ty];
    const float* er = A.emb[ty] + (size_t)node * DD;
    const float* Wt = A.Wtk + (size_t)ty * KF * DD * DK;
    float x[DD];
    #pragma unroll
    for (int d = 0; d < DD; ++d) x[d] = er[d];
    float out[DD];
    #pragma unroll
    for (int k = 0; k < KF; ++k) {
        const float* Wk = Wt + k * DD * DK;
        float nrm = 0.f;
        for (int f = 0; f < DK; ++f) {
            float acc = 0.f;
            for (int d = 0; d < DD; ++d) acc = fmaf(x[d], Wk[d * DK + f], acc);
            acc = leakyf(acc);
            out[k * DK + f] = acc;
            nrm = fmaf(acc, acc, nrm);
        }
        float inv = 1.f / fmaxf(sqrtf(nrm), 1e-12f);
        for (int f = 0; f < DK; ++f) out[k * DK + f] *= inv;
    }
    float* Pr = A.P[ty] + (size_t)node * DD;
    #pragma unroll
    for (int j = 0; j < DD; ++j) Pr[j] = out[j];
}

// ---------------- CSR build ----------------
struct EdgeArgs {
    const int* rows[8]; const int* cols[8];
    int* cnt[8];
    int* cur[8];
    int* colind[8];
    int ebase[9];
};

__global__ void hist_kernel(EdgeArgs A) {
    int g = blockIdx.x * blockDim.x + threadIdx.x;
    if (g >= A.ebase[8]) return;
    int rel = 0;
    while (g >= A.ebase[rel + 1]) ++rel;
    int e = g - A.ebase[rel];
    atomicAdd(&A.cnt[rel][A.rows[rel][e]], 1);
}

struct ScanArgs { int* a[8]; int n[8]; };

__global__ __launch_bounds__(1024) void scan_kernel(ScanArgs A) {
    __shared__ int lds[1024];
    __shared__ int s_carry;
    int* a = A.a[blockIdx.x];
    int n = A.n[blockIdx.x];
    int tid = threadIdx.x;
    if (tid == 0) s_carry = 0;
    __syncthreads();
    for (int base = 0; base < n; base += 1024) {
        int i = base + tid;
        int v = (i < n) ? a[i] : 0;
        lds[tid] = v;
        __syncthreads();
        int x = v;
        for (int off = 1; off < 1024; off <<= 1) {
            int y = (tid >= off) ? lds[tid - off] : 0;
            __syncthreads();
            x += y;
            lds[tid] = x;
            __syncthreads();
        }
        int total = lds[1023];
        int carry = s_carry;
        if (i < n) a[i] = carry + x - v;
        __syncthreads();
        if (tid == 0) s_carry = carry + total;
        __syncthreads();
    }
    if (tid == 0) a[n] = s_carry;
}

__global__ void scatter_kernel(EdgeArgs A) {
    int g = blockIdx.x * blockDim.x + threadIdx.x;
    if (g >= A.ebase[8]) return;
    int rel = 0;
    while (g >= A.ebase[rel + 1]) ++rel;
    int e = g - A.ebase[rel];
    int row = A.rows[rel][e];
    int p = atomicAdd(&A.cur[rel][row], 1);
    A.colind[rel][p] = A.cols[rel][e];
}

// ---------------- sb: per-(rel, col-node) score precompute ----------------
struct SbArgs { const float* Pb[8]; const float* at[8]; float2* sb[8]; int base[9]; int nrel; };

__global__ void sb_kernel(SbArgs A) {
    int g = blockIdx.x * blockDim.x + threadIdx.x;
    if (g >= A.base[A.nrel]) return;
    int rel = 0;
    while (g >= A.base[rel + 1]) ++rel;
    int c = g - A.base[rel];
    const float* p = A.Pb[rel] + (size_t)c * DD;
    const float* a = A.at[rel];
    float s0 = 0.f, s1 = 0.f;
    #pragma unroll
    for (int f = 0; f < DK; ++f) {
        s0 = fmaf(p[f],      a[DK + f],      s0);
        s1 = fmaf(p[DK + f], a[DD + DK + f], s1);
    }
    A.sb[rel][c] = make_float2(s0, s1);
}

// ---------------- fused phase ----------------
struct PhaseArgs {
    const int* rowptr[8]; const int* colind[8];
    const float* Pa[8]; const float* Pb[8];
    const float* at[8]; const float* q[8];
    const float2* sb[8];
    float* z[8]; float* r[8];
    const float* W;
    int rowbase[9];
};

__global__ __launch_bounds__(WPB * 64) void phase_kernel(PhaseArgs A, int totalRows) {
    int wave = blockIdx.x * WPB + (threadIdx.x >> 6);
    int lane = threadIdx.x & 63;
    if (wave >= totalRows) return;
    int rel = 0;
    while (wave >= A.rowbase[rel + 1]) ++rel;
    int u = wave - A.rowbase[rel];

    const int* rowptr = A.rowptr[rel];
    const int* colind = A.colind[rel];
    const float* Pa = A.Pa[rel];
    const float* Pb = A.Pb[rel];
    const float* at_e = A.at[rel];
    const float* qv = A.q[rel];
    const float2* sb = A.sb[rel];
    int beg = rowptr[u], end = rowptr[u + 1];

    bool act = lane < DD;
    // row-side logit half: h_k = sum_f Pa[u][k*25+f] * a_k[f] (once per row)
    float puj  = act ? Pa[(size_t)u * DD + lane] : 0.f;
    float anew = act ? ((lane < DK) ? at_e[lane] : at_e[DD + (lane - DK)]) : 0.f;
    float v0 = (lane < DK) ? puj * anew : 0.f;
    float v1 = puj * anew - v0;
    #pragma unroll
    for (int off = 32; off; off >>= 1) { v0 += __shfl_xor(v0, off); v1 += __shfl_xor(v1, off); }
    float h0 = v0, h1 = v1;

    float ssum = 0.f, acc = 0.f;
    for (int base = beg; base < end; base += 64) {
        int idx = base + lane;
        bool vld = idx < end;
        int cb = vld ? colind[idx] : 0;
        float evl = 0.f;
        if (vld) {
            float2 sc = sb[cb];
            evl = __expf(0.5f * (fmaxf(h0 + sc.x, 0.f) + fmaxf(h1 + sc.y, 0.f)));
        }
        ssum += evl;
        int evi = __float_as_int(evl);   // readlane is int-typed: bit-cast, never value-convert
        int nb = min(64, end - base);
        #pragma unroll 4
        for (int t = 0; t < nb; ++t) {
            int c = __builtin_amdgcn_readlane(cb, t);
            float ev = __int_as_float(__builtin_amdgcn_readlane(evi, t));
            float pcj = act ? Pb[(size_t)c * DD + lane] : 0.f;
            acc = fmaf(ev, pcj, acc);
        }
    }
    #pragma unroll
    for (int off = 32; off; off >>= 1) ssum += __shfl_xor(ssum, off);

    float inv = (ssum > 0.f) ? (1.f / ssum) : 0.f;
    float zl = leakyf(acc * inv);

    // o = z @ W per factor via shfl transpose
    int fcol = act ? ((lane < DK) ? lane : (lane - DK)) : 0;
    int kbase = (act && lane >= DK) ? DK : 0;
    float o = 0.f;
    const float* W = A.W;
    #pragma unroll
    for (int d = 0; d < DK; ++d) {
        float zd = __shfl(zl, kbase + d);
        o = fmaf(zd, W[d * DK + fcol], o);
    }
    float th = act ? tanhf(o) * qv[fcol] : 0.f;
    float t0 = (lane < DK) ? th : 0.f;
    float t1 = th - t0;
    #pragma unroll
    for (int off = 32; off; off >>= 1) { t0 += __shfl_xor(t0, off); t1 += __shfl_xor(t1, off); }
    float m = fmaxf(t0, t1);
    float e0 = __expf(t0 - m), e1 = __expf(t1 - m);
    float rinv = 1.f / (e0 + e1);

    if (act) A.z[rel][(size_t)u * DD + lane] = o;
    if (lane == 0) {
        A.r[rel][(size_t)u * 2 + 0] = e0 * rinv;
        A.r[rel][(size_t)u * 2 + 1] = e1 * rinv;
    }
}

// ---------------- ego ----------------
static __device__ __forceinline__ void l2norm_store(float* dst, const float* acc) {
    #pragma unroll
    for (int k = 0; k < KF; ++k) {
        float nrm = 0.f;
        for (int f = 0; f < DK; ++f) nrm = fmaf(acc[k * DK + f], acc[k * DK + f], nrm);
        float inv = 1.f / fmaxf(sqrtf(nrm), 1e-12f);
        for (int f = 0; f < DK; ++f) dst[k * DK + f] = acc[k * DK + f] * inv;
    }
}

struct EgoArgs { float* P0; float* P1; const float* zz[8]; const float* rr[8]; int n0, n1; };

__global__ void ego_kernel(EgoArgs A) {
    int g = blockIdx.x * blockDim.x + threadIdx.x;
    if (g >= A.n0 + A.n1) return;
    float acc[DD];
    if (g < A.n0) {
        float* Pr = A.P0 + (size_t)g * DD;
        const float* zr = A.zz[0] + (size_t)g * DD;
        float r0 = A.rr[0][(size_t)g * 2], r1 = A.rr[0][(size_t)g * 2 + 1];
        #pragma unroll
        for (int j = 0; j < DD; ++j) acc[j] = fmaf(zr[j], (j < DK ? r0 : r1), Pr[j]);
        l2norm_store(Pr, acc);
    } else {
        int node = g - A.n0;
        float* Pr = A.P1 + (size_t)node * DD;
        #pragma unroll
        for (int j = 0; j < DD; ++j) acc[j] = Pr[j];
        for (int e = 1; e < 8; ++e) {
            const float* zr = A.zz[e] + (size_t)node * DD;
            float r0 = A.rr[e][(size_t)node * 2], r1 = A.rr[e][(size_t)node * 2 + 1];
            #pragma unroll
            for (int j = 0; j < DD; ++j) acc[j] = fmaf(zr[j], (j < DK ? r0 : r1), acc[j]);
        }
        l2norm_store(Pr, acc);
    }
}

static inline int cdiv(int a, int b) { return (a + b - 1) / b; }

extern "C" void kernel_launch(void* const* d_in, const int* in_sizes, int n_in,
                              void* d_out, int out_size, void* d_ws, size_t ws_size,
                              hipStream_t stream) {
    const int* edge[8];
    int E[8];
    for (int e = 0; e < 8; ++e) { edge[e] = (const int*)d_in[e]; E[e] = in_sizes[e] / 2; }
    const float* emb[8];
    int nn[8];
    for (int i = 0; i < 8; ++i) { emb[i] = (const float*)d_in[8 + i]; nn[i] = in_sizes[8 + i] / DD; }
    const float* Wtk = (const float*)d_in[16];
    const float* at  = (const float*)d_in[17];
    const float* W   = (const float*)d_in[18];
    const float* q   = (const float*)d_in[19];
    float* out = (float*)d_out;

    static const int aIdx[8] = {0, 1, 1, 1, 1, 1, 1, 1};
    static const int bIdx[8] = {1, 0, 2, 3, 4, 5, 6, 7};
    int rows[8], ncol[8];
    for (int e = 0; e < 8; ++e) { rows[e] = nn[aIdx[e]]; ncol[e] = nn[bIdx[e]]; }

    // ---- workspace ----
    char* w = (char*)d_ws;
    size_t off = 0;
    auto alloc_f  = [&](size_t n) { float*  p = (float*)(w + off);  off += n * 4; return p; };
    auto alloc_f2 = [&](size_t n) { float2* p = (float2*)(w + off); off += n * 8; return p; };
    auto alloc_i  = [&](size_t n) { int*    p = (int*)(w + off);    off += n * 4; return p; };
    float* P[8]; for (int i = 0; i < 8; ++i) P[i] = alloc_f((size_t)nn[i] * DD);
    float* z[8]; for (int e = 0; e < 8; ++e) z[e] = alloc_f((size_t)rows[e] * DD);
    float* r[8]; for (int e = 0; e < 8; ++e) r[e] = alloc_f((size_t)rows[e] * 2);
    float2* sb[8]; for (int e = 0; e < 8; ++e) sb[e] = alloc_f2((size_t)ncol[e]);
    int* cntrp_all = alloc_i(0);
    int* cntrp[8]; for (int e = 0; e < 8; ++e) cntrp[e] = alloc_i((size_t)rows[e] + 1);
    size_t cnt_total = 0; for (int e = 0; e < 8; ++e) cnt_total += rows[e] + 1;
    int* cur_all = alloc_i(0);
    int* cur[8]; for (int e = 0; e < 8; ++e) cur[e] = alloc_i((size_t)rows[e] + 1);
    int* colind[8]; for (int e = 0; e < 8; ++e) colind[e] = alloc_i((size_t)E[e]);

    const int B = 256;

    // ---- CSR build ----
    hipMemsetAsync(cntrp_all, 0, cnt_total * 4, stream);
    EdgeArgs EA;
    EA.ebase[0] = 0;
    for (int e = 0; e < 8; ++e) {
        EA.rows[e] = edge[e]; EA.cols[e] = edge[e] + E[e];
        EA.cnt[e] = cntrp[e]; EA.cur[e] = cur[e]; EA.colind[e] = colind[e];
        EA.ebase[e + 1] = EA.ebase[e] + E[e];
    }
    int totE = EA.ebase[8];
    hist_kernel<<<cdiv(totE, B), B, 0, stream>>>(EA);
    ScanArgs SA;
    for (int e = 0; e < 8; ++e) { SA.a[e] = cntrp[e]; SA.n[e] = rows[e]; }
    scan_kernel<<<8, 1024, 0, stream>>>(SA);
    hipMemcpyAsync(cur_all, cntrp_all, cnt_total * 4, hipMemcpyDeviceToDevice, stream);
    scatter_kernel<<<cdiv(totE, B), B, 0, stream>>>(EA);

    // ---- fac ----
    FacArgs FA;
    FA.base[0] = 0;
    for (int i = 0; i < 8; ++i) { FA.emb[i] = emb[i]; FA.P[i] = P[i]; FA.base[i + 1] = FA.base[i] + nn[i]; }
    FA.Wtk = Wtk;
    fac_kernel<<<cdiv(FA.base[8], B), B, 0, stream>>>(FA);

    // ---- sb precompute: all 8 relations once; rels 0,1 per-iteration ----
    SbArgs SBall;
    SBall.base[0] = 0;
    for (int e = 0; e < 8; ++e) {
        SBall.Pb[e] = P[bIdx[e]]; SBall.at[e] = at + (size_t)e * KF * DD; SBall.sb[e] = sb[e];
        SBall.base[e + 1] = SBall.base[e] + ncol[e];
    }
    SBall.nrel = 8;
    sb_kernel<<<cdiv(SBall.base[8], B), B, 0, stream>>>(SBall);

    SbArgs SB01 = SBall;
    SB01.nrel = 2;  // rels 0,1 — the only ones whose Pb changes across iterations

    // ---- iterations ----
    PhaseArgs PA;
    PA.rowbase[0] = 0;
    for (int e = 0; e < 8; ++e) {
        PA.rowptr[e] = cntrp[e]; PA.colind[e] = colind[e];
        PA.Pa[e] = P[aIdx[e]];   PA.Pb[e] = P[bIdx[e]];
        PA.at[e] = at + (size_t)e * KF * DD;
        PA.q[e]  = q + (size_t)e * DK;
        PA.sb[e] = sb[e];
        PA.z[e] = z[e]; PA.r[e] = r[e];
        PA.rowbase[e + 1] = PA.rowbase[e] + rows[e];
    }
    PA.W = W;
    int totalRows = PA.rowbase[8];
    EgoArgs GA;
    GA.P0 = P[0]; GA.P1 = P[1]; GA.n0 = nn[0]; GA.n1 = nn[1];
    for (int e = 0; e < 8; ++e) { GA.zz[e] = z[e]; GA.rr[e] = r[e]; }

    for (int it = 0; it < ITERS; ++it) {
        phase_kernel<<<cdiv(totalRows, WPB), WPB * 64, 0, stream>>>(PA, totalRows);
        ego_kernel<<<cdiv(nn[0] + nn[1], B), B, 0, stream>>>(GA);
        sb_kernel<<<cdiv(SB01.base[2], B), B, 0, stream>>>(SB01);
    }

    // ---- output ----
    hipMemcpyAsync(out, P[0], (size_t)nn[0] * DD * 4, hipMemcpyDeviceToDevice, stream);
    hipMemcpyAsync(out + (size_t)nn[0] * DD, P[1], (size_t)nn[1] * DD * 4,
                   hipMemcpyDeviceToDevice, stream);
}

// Round 8
// 1995.050 us; speedup vs baseline: 21.3339x; 1.1597x over previous
//
#include <hip/hip_runtime.h>
#include <math.h>

// GraphEncoder v5 — one-variable bisect from v2.1 (last passing, 2313us).
// ONLY change vs v2.1: P rows padded to 52 floats (16B-aligned) + float4
// gather inner loop (4 edge-groups of 16 lanes) + trivial strided out-copy
// kernel (P stride 52 -> out stride 50). The v3/v4 fusion set (sa precompute,
// fac/ego fusion, fast tanh, direct-out, u16 colind) is ENTIRELY excluded.

#define KF 2
#define DK 25
#define DD 50
#define PS 52   // padded P row stride: 208 B = 13 float4
#define ITERS 4
#define WPB 4

static __device__ __forceinline__ float leakyf(float x) { return x > 0.f ? x : 0.2f * x; }

// ---------------- fac ----------------
struct FacArgs { const float* emb[8]; float* P[8]; const float* Wtk; int base[9]; };

__global__ void fac_kernel(FacArgs A) {
    int g = blockIdx.x * blockDim.x + threadIdx.x;
    if (g >= A.base[8]) return;
    int ty = 0;
    while (g >= A.base[ty + 1]) ++ty;
    int node = g - A.base[ty];
    const float* er = A.emb[ty] + (size_t)node * DD;
    const float* Wt = A.Wtk + (size_t)ty * KF * DD * DK;
    float x[DD];
    #pragma unroll
    for (int d = 0; d < DD; ++d) x[d] = er[d];
    float out[DD];
    #pragma unroll
    for (int k = 0; k < KF; ++k) {
        const float* Wk = Wt + k * DD * DK;
        float nrm = 0.f;
        for (int f = 0; f < DK; ++f) {
            float acc = 0.f;
            for (int d = 0; d < DD; ++d) acc = fmaf(x[d], Wk[d * DK + f], acc);
            acc = leakyf(acc);
            out[k * DK + f] = acc;
            nrm = fmaf(acc, acc, nrm);
        }
        float inv = 1.f / fmaxf(sqrtf(nrm), 1e-12f);
        for (int f = 0; f < DK; ++f) out[k * DK + f] *= inv;
    }
    float* Pr = A.P[ty] + (size_t)node * PS;
    #pragma unroll
    for (int j = 0; j < DD; ++j) Pr[j] = out[j];
    Pr[50] = 0.f; Pr[51] = 0.f;   // zero the pad
}

// ---------------- CSR build ----------------
struct EdgeArgs {
    const int* rows[8]; const int* cols[8];
    int* cnt[8];
    int* cur[8];
    int* colind[8];
    int ebase[9];
};

__global__ void hist_kernel(EdgeArgs A) {
    int g = blockIdx.x * blockDim.x + threadIdx.x;
    if (g >= A.ebase[8]) return;
    int rel = 0;
    while (g >= A.ebase[rel + 1]) ++rel;
    int e = g - A.ebase[rel];
    atomicAdd(&A.cnt[rel][A.rows[rel][e]], 1);
}

struct ScanArgs { int* a[8]; int n[8]; };

__global__ __launch_bounds__(1024) void scan_kernel(ScanArgs A) {
    __shared__ int lds[1024];
    __shared__ int s_carry;
    int* a = A.a[blockIdx.x];
    int n = A.n[blockIdx.x];
    int tid = threadIdx.x;
    if (tid == 0) s_carry = 0;
    __syncthreads();
    for (int base = 0; base < n; base += 1024) {
        int i = base + tid;
        int v = (i < n) ? a[i] : 0;
        lds[tid] = v;
        __syncthreads();
        int x = v;
        for (int off = 1; off < 1024; off <<= 1) {
            int y = (tid >= off) ? lds[tid - off] : 0;
            __syncthreads();
            x += y;
            lds[tid] = x;
            __syncthreads();
        }
        int total = lds[1023];
        int carry = s_carry;
        if (i < n) a[i] = carry + x - v;
        __syncthreads();
        if (tid == 0) s_carry = carry + total;
        __syncthreads();
    }
    if (tid == 0) a[n] = s_carry;
}

__global__ void scatter_kernel(EdgeArgs A) {
    int g = blockIdx.x * blockDim.x + threadIdx.x;
    if (g >= A.ebase[8]) return;
    int rel = 0;
    while (g >= A.ebase[rel + 1]) ++rel;
    int e = g - A.ebase[rel];
    int row = A.rows[rel][e];
    int p = atomicAdd(&A.cur[rel][row], 1);
    A.colind[rel][p] = A.cols[rel][e];
}

// ---------------- sb: per-(rel, col-node) score precompute ----------------
struct SbArgs { const float* Pb[8]; const float* at[8]; float2* sb[8]; int base[9]; int nrel; };

__global__ void sb_kernel(SbArgs A) {
    int g = blockIdx.x * blockDim.x + threadIdx.x;
    if (g >= A.base[A.nrel]) return;
    int rel = 0;
    while (g >= A.base[rel + 1]) ++rel;
    int c = g - A.base[rel];
    const float* p = A.Pb[rel] + (size_t)c * PS;
    const float* a = A.at[rel];
    float s0 = 0.f, s1 = 0.f;
    #pragma unroll
    for (int f = 0; f < DK; ++f) {
        s0 = fmaf(p[f],      a[DK + f],      s0);
        s1 = fmaf(p[DK + f], a[DD + DK + f], s1);
    }
    A.sb[rel][c] = make_float2(s0, s1);
}

// ---------------- fused phase ----------------
struct PhaseArgs {
    const int* rowptr[8]; const int* colind[8];
    const float* Pa[8]; const float* Pb[8];
    const float* at[8]; const float* q[8];
    const float2* sb[8];
    float* z[8]; float* r[8];
    const float* W;
    int rowbase[9];
};

__global__ __launch_bounds__(WPB * 64) void phase_kernel(PhaseArgs A, int totalRows) {
    int wave = blockIdx.x * WPB + (threadIdx.x >> 6);
    int lane = threadIdx.x & 63;
    if (wave >= totalRows) return;
    int rel = 0;
    while (wave >= A.rowbase[rel + 1]) ++rel;
    int u = wave - A.rowbase[rel];

    const int* rowptr = A.rowptr[rel];
    const int* colind = A.colind[rel];
    const float* Pa = A.Pa[rel];
    const float* Pb = A.Pb[rel];
    const float* at_e = A.at[rel];
    const float* qv = A.q[rel];
    const float2* sb = A.sb[rel];
    int beg = rowptr[u], end = rowptr[u + 1];

    bool act = lane < DD;
    // row-side logit half: h_k = sum_f Pa[u][k*25+f] * a_k[f] (butterfly, as v2.1)
    float puj  = act ? Pa[(size_t)u * PS + lane] : 0.f;
    float anew = act ? ((lane < DK) ? at_e[lane] : at_e[DD + (lane - DK)]) : 0.f;
    float v0 = (lane < DK) ? puj * anew : 0.f;
    float v1 = puj * anew - v0;
    #pragma unroll
    for (int off = 32; off; off >>= 1) { v0 += __shfl_xor(v0, off); v1 += __shfl_xor(v1, off); }
    float h0 = v0, h1 = v1;

    // ---- float4 gather inner loop: 4 edge-groups of 16 lanes ----
    int grp4 = lane >> 4, sub4 = lane & 15;
    float ssum = 0.f;
    float4 a4 = make_float4(0.f, 0.f, 0.f, 0.f);

    for (int base = beg; base < end; base += 64) {
        int idx = base + lane;
        bool vld = idx < end;
        int cb = vld ? colind[idx] : 0;
        float evl = 0.f;
        if (vld) {
            float2 sc = sb[cb];
            evl = __expf(0.5f * (fmaxf(h0 + sc.x, 0.f) + fmaxf(h1 + sc.y, 0.f)));
        }
        ssum += evl;
        int nb = min(64, end - base);
        #pragma unroll 2
        for (int t = 0; t < nb; t += 4) {
            int srcl = t + grp4;              // <= 63 always
            int c = __shfl(cb, srcl);
            float ev = __shfl(evl, srcl);     // 0 beyond row end (evl masked)
            const float4* pc = (const float4*)(Pb + (size_t)c * PS);
            float4 v = pc[sub4];              // sub4>=13: pad/next-row, never consumed
            a4.x = fmaf(ev, v.x, a4.x);
            a4.y = fmaf(ev, v.y, a4.y);
            a4.z = fmaf(ev, v.z, a4.z);
            a4.w = fmaf(ev, v.w, a4.w);
        }
    }
    // fold 4 groups (xor 32,16 preserves sub4)
    #pragma unroll
    for (int off = 32; off >= 16; off >>= 1) {
        a4.x += __shfl_xor(a4.x, off);
        a4.y += __shfl_xor(a4.y, off);
        a4.z += __shfl_xor(a4.z, off);
        a4.w += __shfl_xor(a4.w, off);
    }
    #pragma unroll
    for (int off = 32; off; off >>= 1) ssum += __shfl_xor(ssum, off);

    // redistribute: feature j on lane j, sourced from lane j>>2 component j&3
    int src = lane >> 2;
    float fx = __shfl(a4.x, src), fy = __shfl(a4.y, src);
    float fz = __shfl(a4.z, src), fw = __shfl(a4.w, src);
    float za = (lane & 1) ? ((lane & 2) ? fw : fy) : ((lane & 2) ? fz : fx);

    float inv = (ssum > 0.f) ? (1.f / ssum) : 0.f;
    float zl = act ? leakyf(za * inv) : 0.f;

    // o = z @ W per factor via shfl transpose (as v2.1)
    int fcol = act ? ((lane < DK) ? lane : (lane - DK)) : 0;
    int kbase = (act && lane >= DK) ? DK : 0;
    float o = 0.f;
    const float* W = A.W;
    #pragma unroll
    for (int d = 0; d < DK; ++d) {
        float zd = __shfl(zl, kbase + d);
        o = fmaf(zd, W[d * DK + fcol], o);
    }
    float th = act ? tanhf(o) * qv[fcol] : 0.f;
    float t0 = (lane < DK) ? th : 0.f;
    float t1 = th - t0;
    #pragma unroll
    for (int off = 32; off; off >>= 1) { t0 += __shfl_xor(t0, off); t1 += __shfl_xor(t1, off); }
    float m = fmaxf(t0, t1);
    float e0 = __expf(t0 - m), e1 = __expf(t1 - m);
    float rinv = 1.f / (e0 + e1);

    if (act) A.z[rel][(size_t)u * DD + lane] = o;
    if (lane == 0) {
        A.r[rel][(size_t)u * 2 + 0] = e0 * rinv;
        A.r[rel][(size_t)u * 2 + 1] = e1 * rinv;
    }
}

// ---------------- ego (v2.1, stride PS) ----------------
static __device__ __forceinline__ void l2norm_store(float* dst, const float* acc) {
    #pragma unroll
    for (int k = 0; k < KF; ++k) {
        float nrm = 0.f;
        for (int f = 0; f < DK; ++f) nrm = fmaf(acc[k * DK + f], acc[k * DK + f], nrm);
        float inv = 1.f / fmaxf(sqrtf(nrm), 1e-12f);
        for (int f = 0; f < DK; ++f) dst[k * DK + f] = acc[k * DK + f] * inv;
    }
}

struct EgoArgs { float* P0; float* P1; const float* zz[8]; const float* rr[8]; int n0, n1; };

__global__ void ego_kernel(EgoArgs A) {
    int g = blockIdx.x * blockDim.x + threadIdx.x;
    if (g >= A.n0 + A.n1) return;
    float acc[DD];
    if (g < A.n0) {
        float* Pr = A.P0 + (size_t)g * PS;
        const float* zr = A.zz[0] + (size_t)g * DD;
        float r0 = A.rr[0][(size_t)g * 2], r1 = A.rr[0][(size_t)g * 2 + 1];
        #pragma unroll
        for (int j = 0; j < DD; ++j) acc[j] = fmaf(zr[j], (j < DK ? r0 : r1), Pr[j]);
        l2norm_store(Pr, acc);
    } else {
        int node = g - A.n0;
        float* Pr = A.P1 + (size_t)node * PS;
        #pragma unroll
        for (int j = 0; j < DD; ++j) acc[j] = Pr[j];
        for (int e = 1; e < 8; ++e) {
            const float* zr = A.zz[e] + (size_t)node * DD;
            float r0 = A.rr[e][(size_t)node * 2], r1 = A.rr[e][(size_t)node * 2 + 1];
            #pragma unroll
            for (int j = 0; j < DD; ++j) acc[j] = fmaf(zr[j], (j < DK ? r0 : r1), acc[j]);
        }
        l2norm_store(Pr, acc);
    }
}

// ---------------- output: strided copy P(52) -> out(50) ----------------
__global__ void out_kernel(const float* __restrict__ P0, const float* __restrict__ P1,
                           int n0, int n1, float* __restrict__ out) {
    int g = blockIdx.x * blockDim.x + threadIdx.x;
    if (g >= n0 + n1) return;
    const float* src = (g < n0) ? (P0 + (size_t)g * PS) : (P1 + (size_t)(g - n0) * PS);
    float* dst = out + (size_t)g * DD;
    #pragma unroll
    for (int j = 0; j < DD; ++j) dst[j] = src[j];
}

static inline int cdiv(int a, int b) { return (a + b - 1) / b; }

extern "C" void kernel_launch(void* const* d_in, const int* in_sizes, int n_in,
                              void* d_out, int out_size, void* d_ws, size_t ws_size,
                              hipStream_t stream) {
    const int* edge[8];
    int E[8];
    for (int e = 0; e < 8; ++e) { edge[e] = (const int*)d_in[e]; E[e] = in_sizes[e] / 2; }
    const float* emb[8];
    int nn[8];
    for (int i = 0; i < 8; ++i) { emb[i] = (const float*)d_in[8 + i]; nn[i] = in_sizes[8 + i] / DD; }
    const float* Wtk = (const float*)d_in[16];
    const float* at  = (const float*)d_in[17];
    const float* W   = (const float*)d_in[18];
    const float* q   = (const float*)d_in[19];
    float* out = (float*)d_out;

    static const int aIdx[8] = {0, 1, 1, 1, 1, 1, 1, 1};
    static const int bIdx[8] = {1, 0, 2, 3, 4, 5, 6, 7};
    int rows[8], ncol[8];
    for (int e = 0; e < 8; ++e) { rows[e] = nn[aIdx[e]]; ncol[e] = nn[bIdx[e]]; }

    // ---- workspace (v2.1 layout, P stride 52; total ~112.4 MB < proven 113.76) ----
    char* w = (char*)d_ws;
    size_t off = 0;
    auto alloc_f  = [&](size_t n) { float*  p = (float*)(w + off);  off += n * 4; return p; };
    auto alloc_f2 = [&](size_t n) { float2* p = (float2*)(w + off); off += n * 8; return p; };
    auto alloc_i  = [&](size_t n) { int*    p = (int*)(w + off);    off += n * 4; return p; };
    float* P[8]; for (int i = 0; i < 8; ++i) P[i] = alloc_f((size_t)nn[i] * PS);
    float* z[8]; for (int e = 0; e < 8; ++e) z[e] = alloc_f((size_t)rows[e] * DD);
    float* r[8]; for (int e = 0; e < 8; ++e) r[e] = alloc_f((size_t)rows[e] * 2);
    float2* sb[8]; for (int e = 0; e < 8; ++e) sb[e] = alloc_f2((size_t)ncol[e]);
    int* cntrp_all = alloc_i(0);
    int* cntrp[8]; for (int e = 0; e < 8; ++e) cntrp[e] = alloc_i((size_t)rows[e] + 1);
    size_t cnt_total = 0; for (int e = 0; e < 8; ++e) cnt_total += rows[e] + 1;
    int* cur_all = alloc_i(0);
    int* cur[8]; for (int e = 0; e < 8; ++e) cur[e] = alloc_i((size_t)rows[e] + 1);
    int* colind[8]; for (int e = 0; e < 8; ++e) colind[e] = alloc_i((size_t)E[e]);
    (void)ws_size;

    const int B = 256;

    // ---- CSR build ----
    hipMemsetAsync(cntrp_all, 0, cnt_total * 4, stream);
    EdgeArgs EA;
    EA.ebase[0] = 0;
    for (int e = 0; e < 8; ++e) {
        EA.rows[e] = edge[e]; EA.cols[e] = edge[e] + E[e];
        EA.cnt[e] = cntrp[e]; EA.cur[e] = cur[e]; EA.colind[e] = colind[e];
        EA.ebase[e + 1] = EA.ebase[e] + E[e];
    }
    int totE = EA.ebase[8];
    hist_kernel<<<cdiv(totE, B), B, 0, stream>>>(EA);
    ScanArgs SA;
    for (int e = 0; e < 8; ++e) { SA.a[e] = cntrp[e]; SA.n[e] = rows[e]; }
    scan_kernel<<<8, 1024, 0, stream>>>(SA);
    hipMemcpyAsync(cur_all, cntrp_all, cnt_total * 4, hipMemcpyDeviceToDevice, stream);
    scatter_kernel<<<cdiv(totE, B), B, 0, stream>>>(EA);

    // ---- fac ----
    FacArgs FA;
    FA.base[0] = 0;
    for (int i = 0; i < 8; ++i) { FA.emb[i] = emb[i]; FA.P[i] = P[i]; FA.base[i + 1] = FA.base[i] + nn[i]; }
    FA.Wtk = Wtk;
    fac_kernel<<<cdiv(FA.base[8], B), B, 0, stream>>>(FA);

    // ---- sb precompute: all 8 relations once; rels 0,1 per-iteration ----
    SbArgs SBall;
    SBall.base[0] = 0;
    for (int e = 0; e < 8; ++e) {
        SBall.Pb[e] = P[bIdx[e]]; SBall.at[e] = at + (size_t)e * KF * DD; SBall.sb[e] = sb[e];
        SBall.base[e + 1] = SBall.base[e] + ncol[e];
    }
    SBall.nrel = 8;
    sb_kernel<<<cdiv(SBall.base[8], B), B, 0, stream>>>(SBall);

    SbArgs SB01 = SBall;
    SB01.nrel = 2;

    // ---- iterations ----
    PhaseArgs PA;
    PA.rowbase[0] = 0;
    for (int e = 0; e < 8; ++e) {
        PA.rowptr[e] = cntrp[e]; PA.colind[e] = colind[e];
        PA.Pa[e] = P[aIdx[e]];   PA.Pb[e] = P[bIdx[e]];
        PA.at[e] = at + (size_t)e * KF * DD;
        PA.q[e]  = q + (size_t)e * DK;
        PA.sb[e] = sb[e];
        PA.z[e] = z[e]; PA.r[e] = r[e];
        PA.rowbase[e + 1] = PA.rowbase[e] + rows[e];
    }
    PA.W = W;
    int totalRows = PA.rowbase[8];
    EgoArgs GA;
    GA.P0 = P[0]; GA.P1 = P[1]; GA.n0 = nn[0]; GA.n1 = nn[1];
    for (int e = 0; e < 8; ++e) { GA.zz[e] = z[e]; GA.rr[e] = r[e]; }

    for (int it = 0; it < ITERS; ++it) {
        phase_kernel<<<cdiv(totalRows, WPB), WPB * 64, 0, stream>>>(PA, totalRows);
        ego_kernel<<<cdiv(nn[0] + nn[1], B), B, 0, stream>>>(GA);
        sb_kernel<<<cdiv(SB01.base[2], B), B, 0, stream>>>(SB01);
    }

    // ---- output: strided copy ----
    out_kernel<<<cdiv(nn[0] + nn[1], B), B, 0, stream>>>(P[0], P[1], nn[0], nn[1], out);
}

// Round 9
// 1898.682 us; speedup vs baseline: 22.4167x; 1.0508x over previous
//
#include <hip/hip_runtime.h>
#include <math.h>

// GraphEncoder v6 = v5 (passed, 1995us) + ONE new variable:
//   sa (row-side attention logit) precomputed by a standalone score01_kernel
//   (same proven pattern as sb_kernel; NOT the v3/v4 fac/ego fusion).
// Memory bookkeeping: cur[] deleted (scatter bumps cntrp in place; rowptr
// reconstructed as inclusive ends), D2D memcpy deleted. ws = 113.48 MB,
// below the proven-safe 113.76 MB (v1).

#define KF 2
#define DK 25
#define DD 50
#define PS 52   // padded P row stride: 208 B = 13 float4
#define ITERS 4
#define WPB 4

static __device__ __forceinline__ float leakyf(float x) { return x > 0.f ? x : 0.2f * x; }

// at[e] is [2][50]: factor k at a+k*50; entries 0..24 row-side, 25..49 col-side.
static __device__ __forceinline__ float2 score_row50(const float* p, const float* a) {
    float s0 = 0.f, s1 = 0.f;
    #pragma unroll
    for (int f = 0; f < DK; ++f) {
        s0 = fmaf(p[f],      a[f],      s0);
        s1 = fmaf(p[DK + f], a[50 + f], s1);
    }
    return make_float2(s0, s1);
}
static __device__ __forceinline__ float2 score_col50(const float* p, const float* a) {
    float s0 = 0.f, s1 = 0.f;
    #pragma unroll
    for (int f = 0; f < DK; ++f) {
        s0 = fmaf(p[f],      a[25 + f], s0);
        s1 = fmaf(p[DK + f], a[75 + f], s1);
    }
    return make_float2(s0, s1);
}

// ---------------- fac (unchanged from v5) ----------------
struct FacArgs { const float* emb[8]; float* P[8]; const float* Wtk; int base[9]; };

__global__ void fac_kernel(FacArgs A) {
    int g = blockIdx.x * blockDim.x + threadIdx.x;
    if (g >= A.base[8]) return;
    int ty = 0;
    while (g >= A.base[ty + 1]) ++ty;
    int node = g - A.base[ty];
    const float* er = A.emb[ty] + (size_t)node * DD;
    const float* Wt = A.Wtk + (size_t)ty * KF * DD * DK;
    float x[DD];
    #pragma unroll
    for (int d = 0; d < DD; ++d) x[d] = er[d];
    float out[DD];
    #pragma unroll
    for (int k = 0; k < KF; ++k) {
        const float* Wk = Wt + k * DD * DK;
        float nrm = 0.f;
        for (int f = 0; f < DK; ++f) {
            float acc = 0.f;
            for (int d = 0; d < DD; ++d) acc = fmaf(x[d], Wk[d * DK + f], acc);
            acc = leakyf(acc);
            out[k * DK + f] = acc;
            nrm = fmaf(acc, acc, nrm);
        }
        float inv = 1.f / fmaxf(sqrtf(nrm), 1e-12f);
        for (int f = 0; f < DK; ++f) out[k * DK + f] *= inv;
    }
    float* Pr = A.P[ty] + (size_t)node * PS;
    #pragma unroll
    for (int j = 0; j < DD; ++j) Pr[j] = out[j];
    Pr[50] = 0.f; Pr[51] = 0.f;
}

// ---------------- CSR build (cur eliminated: cntrp doubles as cursor) ----------------
struct EdgeArgs {
    const int* rows[8]; const int* cols[8];
    int* cnt[8];
    int* colind[8];
    int ebase[9];
};

__global__ void hist_kernel(EdgeArgs A) {
    int g = blockIdx.x * blockDim.x + threadIdx.x;
    if (g >= A.ebase[8]) return;
    int rel = 0;
    while (g >= A.ebase[rel + 1]) ++rel;
    int e = g - A.ebase[rel];
    atomicAdd(&A.cnt[rel][A.rows[rel][e]], 1);
}

struct ScanArgs { int* a[8]; int n[8]; };

__global__ __launch_bounds__(1024) void scan_kernel(ScanArgs A) {
    __shared__ int lds[1024];
    __shared__ int s_carry;
    int* a = A.a[blockIdx.x];
    int n = A.n[blockIdx.x];
    int tid = threadIdx.x;
    if (tid == 0) s_carry = 0;
    __syncthreads();
    for (int base = 0; base < n; base += 1024) {
        int i = base + tid;
        int v = (i < n) ? a[i] : 0;
        lds[tid] = v;
        __syncthreads();
        int x = v;
        for (int off = 1; off < 1024; off <<= 1) {
            int y = (tid >= off) ? lds[tid - off] : 0;
            __syncthreads();
            x += y;
            lds[tid] = x;
            __syncthreads();
        }
        int total = lds[1023];
        int carry = s_carry;
        if (i < n) a[i] = carry + x - v;   // exclusive prefix
        __syncthreads();
        if (tid == 0) s_carry = carry + total;
        __syncthreads();
    }
    if (tid == 0) a[n] = s_carry;
}

// scatter bumps cnt in place; afterwards cnt[i] == inclusive end of row i.
__global__ void scatter_kernel(EdgeArgs A) {
    int g = blockIdx.x * blockDim.x + threadIdx.x;
    if (g >= A.ebase[8]) return;
    int rel = 0;
    while (g >= A.ebase[rel + 1]) ++rel;
    int e = g - A.ebase[rel];
    int row = A.rows[rel][e];
    int p = atomicAdd(&A.cnt[rel][row], 1);
    A.colind[rel][p] = A.cols[rel][e];
}

// ---------------- sb init for static relations 2..7 ----------------
struct SbArgs { const float* Pb[6]; const float* at[6]; float2* sb[6]; int base[7]; };

__global__ void sb_kernel(SbArgs A) {
    int g = blockIdx.x * blockDim.x + threadIdx.x;
    if (g >= A.base[6]) return;
    int rel = 0;
    while (g >= A.base[rel + 1]) ++rel;
    int c = g - A.base[rel];
    const float* p = A.Pb[rel] + (size_t)c * PS;
    A.sb[rel][c] = score_col50(p, A.at[rel]);
}

// ---------------- score01: per-iteration sa (all rels) + sb0/sb1 ----------------
struct ScoreArgs {
    const float* P0; const float* P1;
    const float* at;                 // [8][2][50]
    float2* sa[8]; float2* sb0; float2* sb1;
    int n0, n1;
};

__global__ void score01_kernel(ScoreArgs A) {
    int g = blockIdx.x * blockDim.x + threadIdx.x;
    if (g >= A.n0 + A.n1) return;
    if (g < A.n0) {
        const float* p = A.P0 + (size_t)g * PS;
        float pr[DD];
        #pragma unroll
        for (int j = 0; j < DD; ++j) pr[j] = p[j];
        A.sa[0][g] = score_row50(pr, A.at + 0);     // rel 0 rows are type 0
        A.sb1[g]   = score_col50(pr, A.at + 100);   // rel 1 cols are type 0
    } else {
        int node = g - A.n0;
        const float* p = A.P1 + (size_t)node * PS;
        float pr[DD];
        #pragma unroll
        for (int j = 0; j < DD; ++j) pr[j] = p[j];
        #pragma unroll
        for (int e = 1; e < 8; ++e) A.sa[e][node] = score_row50(pr, A.at + e * 100);
        A.sb0[node] = score_col50(pr, A.at + 0);    // rel 0 cols are type 1
    }
}

// ---------------- fused phase (v5 inner loop; h from sa) ----------------
struct PhaseArgs {
    const int* rowptr[8]; const int* colind[8];
    const float* Pb[8];
    const float* q[8];
    const float2* sa[8]; const float2* sb[8];
    float* z[8]; float* r[8];
    const float* W;
    int rowbase[9];
};

__global__ __launch_bounds__(WPB * 64) void phase_kernel(PhaseArgs A, int totalRows) {
    int wave = blockIdx.x * WPB + (threadIdx.x >> 6);
    int lane = threadIdx.x & 63;
    if (wave >= totalRows) return;
    int rel = 0;
    while (wave >= A.rowbase[rel + 1]) ++rel;
    int u = wave - A.rowbase[rel];

    const int* rowptr = A.rowptr[rel];   // inclusive ends; beg(u) = u? rowptr[u-1]:0
    const int* colind = A.colind[rel];
    const float* Pb = A.Pb[rel];
    const float* qv = A.q[rel];
    const float2* sb = A.sb[rel];
    float2 h = A.sa[rel][u];
    int beg = u ? rowptr[u - 1] : 0;
    int end = rowptr[u];

    bool act = lane < DD;
    int grp4 = lane >> 4, sub4 = lane & 15;
    float ssum = 0.f;
    float4 a4 = make_float4(0.f, 0.f, 0.f, 0.f);

    for (int base = beg; base < end; base += 64) {
        int idx = base + lane;
        bool vld = idx < end;
        int cb = vld ? colind[idx] : 0;
        float evl = 0.f;
        if (vld) {
            float2 sc = sb[cb];
            evl = __expf(0.5f * (fmaxf(h.x + sc.x, 0.f) + fmaxf(h.y + sc.y, 0.f)));
        }
        ssum += evl;
        int nb = min(64, end - base);
        #pragma unroll 2
        for (int t = 0; t < nb; t += 4) {
            int srcl = t + grp4;
            int c = __shfl(cb, srcl);
            float ev = __shfl(evl, srcl);
            const float4* pc = (const float4*)(Pb + (size_t)c * PS);
            float4 v = pc[sub4];
            a4.x = fmaf(ev, v.x, a4.x);
            a4.y = fmaf(ev, v.y, a4.y);
            a4.z = fmaf(ev, v.z, a4.z);
            a4.w = fmaf(ev, v.w, a4.w);
        }
    }
    #pragma unroll
    for (int off = 32; off >= 16; off >>= 1) {
        a4.x += __shfl_xor(a4.x, off);
        a4.y += __shfl_xor(a4.y, off);
        a4.z += __shfl_xor(a4.z, off);
        a4.w += __shfl_xor(a4.w, off);
    }
    #pragma unroll
    for (int off = 32; off; off >>= 1) ssum += __shfl_xor(ssum, off);

    int src = lane >> 2;
    float fx = __shfl(a4.x, src), fy = __shfl(a4.y, src);
    float fz = __shfl(a4.z, src), fw = __shfl(a4.w, src);
    float za = (lane & 1) ? ((lane & 2) ? fw : fy) : ((lane & 2) ? fz : fx);

    float inv = (ssum > 0.f) ? (1.f / ssum) : 0.f;
    float zl = act ? leakyf(za * inv) : 0.f;

    int fcol = act ? ((lane < DK) ? lane : (lane - DK)) : 0;
    int kbase = (act && lane >= DK) ? DK : 0;
    float o = 0.f;
    const float* W = A.W;
    #pragma unroll
    for (int d = 0; d < DK; ++d) {
        float zd = __shfl(zl, kbase + d);
        o = fmaf(zd, W[d * DK + fcol], o);
    }
    float th = act ? tanhf(o) * qv[fcol] : 0.f;
    float t0 = (lane < DK) ? th : 0.f;
    float t1 = th - t0;
    #pragma unroll
    for (int off = 32; off; off >>= 1) { t0 += __shfl_xor(t0, off); t1 += __shfl_xor(t1, off); }
    float m = fmaxf(t0, t1);
    float e0 = __expf(t0 - m), e1 = __expf(t1 - m);
    float rinv = 1.f / (e0 + e1);

    if (act) A.z[rel][(size_t)u * DD + lane] = o;
    if (lane == 0) {
        A.r[rel][(size_t)u * 2 + 0] = e0 * rinv;
        A.r[rel][(size_t)u * 2 + 1] = e1 * rinv;
    }
}

// ---------------- ego (unchanged from v5) ----------------
static __device__ __forceinline__ void l2norm_store(float* dst, const float* acc) {
    #pragma unroll
    for (int k = 0; k < KF; ++k) {
        float nrm = 0.f;
        for (int f = 0; f < DK; ++f) nrm = fmaf(acc[k * DK + f], acc[k * DK + f], nrm);
        float inv = 1.f / fmaxf(sqrtf(nrm), 1e-12f);
        for (int f = 0; f < DK; ++f) dst[k * DK + f] = acc[k * DK + f] * inv;
    }
}

struct EgoArgs { float* P0; float* P1; const float* zz[8]; const float* rr[8]; int n0, n1; };

__global__ void ego_kernel(EgoArgs A) {
    int g = blockIdx.x * blockDim.x + threadIdx.x;
    if (g >= A.n0 + A.n1) return;
    float acc[DD];
    if (g < A.n0) {
        float* Pr = A.P0 + (size_t)g * PS;
        const float* zr = A.zz[0] + (size_t)g * DD;
        float r0 = A.rr[0][(size_t)g * 2], r1 = A.rr[0][(size_t)g * 2 + 1];
        #pragma unroll
        for (int j = 0; j < DD; ++j) acc[j] = fmaf(zr[j], (j < DK ? r0 : r1), Pr[j]);
        l2norm_store(Pr, acc);
    } else {
        int node = g - A.n0;
        float* Pr = A.P1 + (size_t)node * PS;
        #pragma unroll
        for (int j = 0; j < DD; ++j) acc[j] = Pr[j];
        for (int e = 1; e < 8; ++e) {
            const float* zr = A.zz[e] + (size_t)node * DD;
            float r0 = A.rr[e][(size_t)node * 2], r1 = A.rr[e][(size_t)node * 2 + 1];
            #pragma unroll
            for (int j = 0; j < DD; ++j) acc[j] = fmaf(zr[j], (j < DK ? r0 : r1), acc[j]);
        }
        l2norm_store(Pr, acc);
    }
}

// ---------------- output: strided copy P(52) -> out(50) ----------------
__global__ void out_kernel(const float* __restrict__ P0, const float* __restrict__ P1,
                           int n0, int n1, float* __restrict__ out) {
    int g = blockIdx.x * blockDim.x + threadIdx.x;
    if (g >= n0 + n1) return;
    const float* src = (g < n0) ? (P0 + (size_t)g * PS) : (P1 + (size_t)(g - n0) * PS);
    float* dst = out + (size_t)g * DD;
    #pragma unroll
    for (int j = 0; j < DD; ++j) dst[j] = src[j];
}

static inline int cdiv(int a, int b) { return (a + b - 1) / b; }

extern "C" void kernel_launch(void* const* d_in, const int* in_sizes, int n_in,
                              void* d_out, int out_size, void* d_ws, size_t ws_size,
                              hipStream_t stream) {
    const int* edge[8];
    int E[8];
    for (int e = 0; e < 8; ++e) { edge[e] = (const int*)d_in[e]; E[e] = in_sizes[e] / 2; }
    const float* emb[8];
    int nn[8];
    for (int i = 0; i < 8; ++i) { emb[i] = (const float*)d_in[8 + i]; nn[i] = in_sizes[8 + i] / DD; }
    const float* Wtk = (const float*)d_in[16];
    const float* at  = (const float*)d_in[17];
    const float* W   = (const float*)d_in[18];
    const float* q   = (const float*)d_in[19];
    float* out = (float*)d_out;

    static const int aIdx[8] = {0, 1, 1, 1, 1, 1, 1, 1};
    static const int bIdx[8] = {1, 0, 2, 3, 4, 5, 6, 7};
    int rows[8], ncol[8];
    for (int e = 0; e < 8; ++e) { rows[e] = nn[aIdx[e]]; ncol[e] = nn[bIdx[e]]; }

    // ---- workspace: P(52), z, r, sb, sa, cntrp, colind = 113.48 MB ----
    char* w = (char*)d_ws;
    size_t off = 0;
    auto alloc_f  = [&](size_t n) { float*  p = (float*)(w + off);  off += n * 4; return p; };
    auto alloc_f2 = [&](size_t n) { float2* p = (float2*)(w + off); off += n * 8; return p; };
    auto alloc_i  = [&](size_t n) { int*    p = (int*)(w + off);    off += n * 4; return p; };
    float* P[8]; for (int i = 0; i < 8; ++i) P[i] = alloc_f((size_t)nn[i] * PS);
    float* z[8]; for (int e = 0; e < 8; ++e) z[e] = alloc_f((size_t)rows[e] * DD);
    float* r[8]; for (int e = 0; e < 8; ++e) r[e] = alloc_f((size_t)rows[e] * 2);
    float2* sb[8]; for (int e = 0; e < 8; ++e) sb[e] = alloc_f2((size_t)ncol[e]);
    float2* sa[8]; for (int e = 0; e < 8; ++e) sa[e] = alloc_f2((size_t)rows[e]);
    int* cntrp_all = alloc_i(0);
    int* cntrp[8]; for (int e = 0; e < 8; ++e) cntrp[e] = alloc_i((size_t)rows[e] + 1);
    size_t cnt_total = 0; for (int e = 0; e < 8; ++e) cnt_total += rows[e] + 1;
    int* colind[8]; for (int e = 0; e < 8; ++e) colind[e] = alloc_i((size_t)E[e]);
    (void)ws_size;

    const int B = 256;

    // ---- CSR build ----
    hipMemsetAsync(cntrp_all, 0, cnt_total * 4, stream);
    EdgeArgs EA;
    EA.ebase[0] = 0;
    for (int e = 0; e < 8; ++e) {
        EA.rows[e] = edge[e]; EA.cols[e] = edge[e] + E[e];
        EA.cnt[e] = cntrp[e]; EA.colind[e] = colind[e];
        EA.ebase[e + 1] = EA.ebase[e] + E[e];
    }
    int totE = EA.ebase[8];
    hist_kernel<<<cdiv(totE, B), B, 0, stream>>>(EA);
    ScanArgs SA;
    for (int e = 0; e < 8; ++e) { SA.a[e] = cntrp[e]; SA.n[e] = rows[e]; }
    scan_kernel<<<8, 1024, 0, stream>>>(SA);
    scatter_kernel<<<cdiv(totE, B), B, 0, stream>>>(EA);   // leaves cntrp[i] = inclusive end

    // ---- fac ----
    FacArgs FA;
    FA.base[0] = 0;
    for (int i = 0; i < 8; ++i) { FA.emb[i] = emb[i]; FA.P[i] = P[i]; FA.base[i + 1] = FA.base[i] + nn[i]; }
    FA.Wtk = Wtk;
    fac_kernel<<<cdiv(FA.base[8], B), B, 0, stream>>>(FA);

    // ---- static sb (rels 2..7) once ----
    SbArgs SBs;
    SBs.base[0] = 0;
    for (int e = 2; e < 8; ++e) {
        SBs.Pb[e - 2] = P[bIdx[e]];
        SBs.at[e - 2] = at + (size_t)e * KF * DD;
        SBs.sb[e - 2] = sb[e];
        SBs.base[e - 1] = SBs.base[e - 2] + ncol[e];
    }
    sb_kernel<<<cdiv(SBs.base[6], B), B, 0, stream>>>(SBs);

    // ---- dynamic scores (sa all rels + sb0/sb1): init + per-iteration ----
    ScoreArgs SC;
    SC.P0 = P[0]; SC.P1 = P[1]; SC.at = at;
    for (int e = 0; e < 8; ++e) SC.sa[e] = sa[e];
    SC.sb0 = sb[0]; SC.sb1 = sb[1];
    SC.n0 = nn[0]; SC.n1 = nn[1];
    score01_kernel<<<cdiv(nn[0] + nn[1], B), B, 0, stream>>>(SC);

    // ---- iterations ----
    PhaseArgs PA;
    PA.rowbase[0] = 0;
    for (int e = 0; e < 8; ++e) {
        PA.rowptr[e] = cntrp[e]; PA.colind[e] = colind[e];
        PA.Pb[e] = P[bIdx[e]];
        PA.q[e]  = q + (size_t)e * DK;
        PA.sa[e] = sa[e]; PA.sb[e] = sb[e];
        PA.z[e] = z[e]; PA.r[e] = r[e];
        PA.rowbase[e + 1] = PA.rowbase[e] + rows[e];
    }
    PA.W = W;
    int totalRows = PA.rowbase[8];
    EgoArgs GA;
    GA.P0 = P[0]; GA.P1 = P[1]; GA.n0 = nn[0]; GA.n1 = nn[1];
    for (int e = 0; e < 8; ++e) { GA.zz[e] = z[e]; GA.rr[e] = r[e]; }

    for (int it = 0; it < ITERS; ++it) {
        phase_kernel<<<cdiv(totalRows, WPB), WPB * 64, 0, stream>>>(PA, totalRows);
        ego_kernel<<<cdiv(nn[0] + nn[1], B), B, 0, stream>>>(GA);
        score01_kernel<<<cdiv(nn[0] + nn[1], B), B, 0, stream>>>(SC);
    }

    // ---- output ----
    out_kernel<<<cdiv(nn[0] + nn[1], B), B, 0, stream>>>(P[0], P[1], nn[0], nn[1], out);
}

// Round 10
// 1747.208 us; speedup vs baseline: 24.3601x; 1.0867x over previous
//
#include <hip/hip_runtime.h>
#include <math.h>

// GraphEncoder v7 = v6 (passed, 1899us) + flat global CSR with u16 colind
// (7.6 MB, L2-resident -> scatter writebacks collapse) + 3-kernel hierarchical
// scan (v6's 8-block scan used only 8 CUs). u16 is the one variable from the
// v4 crash-suspect set being re-tested here.

#define KF 2
#define DK 25
#define DD 50
#define PS 52   // padded P row stride: 208 B = 13 float4
#define ITERS 4
#define WPB 4

static __device__ __forceinline__ float leakyf(float x) { return x > 0.f ? x : 0.2f * x; }

// at[e] is [2][50]: factor k at a+k*50; 0..24 row-side, 25..49 col-side.
static __device__ __forceinline__ float2 score_row50(const float* p, const float* a) {
    float s0 = 0.f, s1 = 0.f;
    #pragma unroll
    for (int f = 0; f < DK; ++f) {
        s0 = fmaf(p[f],      a[f],      s0);
        s1 = fmaf(p[DK + f], a[50 + f], s1);
    }
    return make_float2(s0, s1);
}
static __device__ __forceinline__ float2 score_col50(const float* p, const float* a) {
    float s0 = 0.f, s1 = 0.f;
    #pragma unroll
    for (int f = 0; f < DK; ++f) {
        s0 = fmaf(p[f],      a[25 + f], s0);
        s1 = fmaf(p[DK + f], a[75 + f], s1);
    }
    return make_float2(s0, s1);
}

// ---------------- fac ----------------
struct FacArgs { const float* emb[8]; float* P[8]; const float* Wtk; int base[9]; };

__global__ void fac_kernel(FacArgs A) {
    int g = blockIdx.x * blockDim.x + threadIdx.x;
    if (g >= A.base[8]) return;
    int ty = 0;
    while (g >= A.base[ty + 1]) ++ty;
    int node = g - A.base[ty];
    const float* er = A.emb[ty] + (size_t)node * DD;
    const float* Wt = A.Wtk + (size_t)ty * KF * DD * DK;
    float x[DD];
    #pragma unroll
    for (int d = 0; d < DD; ++d) x[d] = er[d];
    float out[DD];
    #pragma unroll
    for (int k = 0; k < KF; ++k) {
        const float* Wk = Wt + k * DD * DK;
        float nrm = 0.f;
        for (int f = 0; f < DK; ++f) {
            float acc = 0.f;
            for (int d = 0; d < DD; ++d) acc = fmaf(x[d], Wk[d * DK + f], acc);
            acc = leakyf(acc);
            out[k * DK + f] = acc;
            nrm = fmaf(acc, acc, nrm);
        }
        float inv = 1.f / fmaxf(sqrtf(nrm), 1e-12f);
        for (int f = 0; f < DK; ++f) out[k * DK + f] *= inv;
    }
    float* Pr = A.P[ty] + (size_t)node * PS;
    #pragma unroll
    for (int j = 0; j < DD; ++j) Pr[j] = out[j];
    Pr[50] = 0.f; Pr[51] = 0.f;
}

// ---------------- flat CSR build ----------------
struct EdgeArgs {
    const int* rows[8]; const int* cols[8];
    int* cnt;                  // [totalRows] global-row counts -> rowptr
    unsigned short* colind;    // [totE] flat
    int ebase[9];
    int rowbase[8];
};

__global__ void hist_kernel(EdgeArgs A) {
    int g = blockIdx.x * blockDim.x + threadIdx.x;
    if (g >= A.ebase[8]) return;
    int rel = 0;
    while (g >= A.ebase[rel + 1]) ++rel;
    int e = g - A.ebase[rel];
    atomicAdd(&A.cnt[A.rowbase[rel] + A.rows[rel][e]], 1);
}

// 3-kernel hierarchical exclusive scan over cnt[0..n)
__global__ __launch_bounds__(1024) void scan_part_kernel(int* a, int n, int* bsum) {
    __shared__ int lds[1024];
    int tid = threadIdx.x;
    int i = blockIdx.x * 1024 + tid;
    int v = (i < n) ? a[i] : 0;
    lds[tid] = v;
    __syncthreads();
    int x = v;
    for (int off = 1; off < 1024; off <<= 1) {
        int y = (tid >= off) ? lds[tid - off] : 0;
        __syncthreads();
        x += y;
        lds[tid] = x;
        __syncthreads();
    }
    if (i < n) a[i] = x - v;              // exclusive within chunk
    if (tid == 1023) bsum[blockIdx.x] = x; // chunk total
}

__global__ __launch_bounds__(1024) void scan_bsum_kernel(int* bsum, int nb) {
    __shared__ int lds[1024];
    int tid = threadIdx.x;
    int v = (tid < nb) ? bsum[tid] : 0;
    lds[tid] = v;
    __syncthreads();
    int x = v;
    for (int off = 1; off < 1024; off <<= 1) {
        int y = (tid >= off) ? lds[tid - off] : 0;
        __syncthreads();
        x += y;
        lds[tid] = x;
        __syncthreads();
    }
    if (tid < nb) bsum[tid] = x - v;      // exclusive chunk offsets
}

__global__ __launch_bounds__(1024) void add_off_kernel(int* a, int n, const int* bsum) {
    int i = blockIdx.x * 1024 + threadIdx.x;
    if (i < n) a[i] += bsum[blockIdx.x];
}

// scatter bumps cnt in place; afterwards cnt[w] == inclusive end of global row w.
__global__ void scatter_kernel(EdgeArgs A) {
    int g = blockIdx.x * blockDim.x + threadIdx.x;
    if (g >= A.ebase[8]) return;
    int rel = 0;
    while (g >= A.ebase[rel + 1]) ++rel;
    int e = g - A.ebase[rel];
    int p = atomicAdd(&A.cnt[A.rowbase[rel] + A.rows[rel][e]], 1);
    A.colind[p] = (unsigned short)A.cols[rel][e];
}

// ---------------- sb init for static relations 2..7 ----------------
struct SbArgs { const float* Pb[6]; const float* at[6]; float2* sb[6]; int base[7]; };

__global__ void sb_kernel(SbArgs A) {
    int g = blockIdx.x * blockDim.x + threadIdx.x;
    if (g >= A.base[6]) return;
    int rel = 0;
    while (g >= A.base[rel + 1]) ++rel;
    int c = g - A.base[rel];
    const float* p = A.Pb[rel] + (size_t)c * PS;
    A.sb[rel][c] = score_col50(p, A.at[rel]);
}

// ---------------- score01: per-iteration sa (all rels) + sb0/sb1 ----------------
struct ScoreArgs {
    const float* P0; const float* P1;
    const float* at;
    float2* sa[8]; float2* sb0; float2* sb1;
    int n0, n1;
};

__global__ void score01_kernel(ScoreArgs A) {
    int g = blockIdx.x * blockDim.x + threadIdx.x;
    if (g >= A.n0 + A.n1) return;
    if (g < A.n0) {
        const float* p = A.P0 + (size_t)g * PS;
        float pr[DD];
        #pragma unroll
        for (int j = 0; j < DD; ++j) pr[j] = p[j];
        A.sa[0][g] = score_row50(pr, A.at + 0);
        A.sb1[g]   = score_col50(pr, A.at + 100);
    } else {
        int node = g - A.n0;
        const float* p = A.P1 + (size_t)node * PS;
        float pr[DD];
        #pragma unroll
        for (int j = 0; j < DD; ++j) pr[j] = p[j];
        #pragma unroll
        for (int e = 1; e < 8; ++e) A.sa[e][node] = score_row50(pr, A.at + e * 100);
        A.sb0[node] = score_col50(pr, A.at + 0);
    }
}

// ---------------- fused phase ----------------
struct PhaseArgs {
    const int* rowptr;               // [totalRows] inclusive ends (flat)
    const unsigned short* colind;    // flat
    const float* Pb[8];
    const float* q[8];
    const float2* sa[8]; const float2* sb[8];
    float* z[8]; float* r[8];
    const float* W;
    int rowbase[9];
};

__global__ __launch_bounds__(WPB * 64) void phase_kernel(PhaseArgs A, int totalRows) {
    int wave = blockIdx.x * WPB + (threadIdx.x >> 6);
    int lane = threadIdx.x & 63;
    if (wave >= totalRows) return;
    int rel = 0;
    while (wave >= A.rowbase[rel + 1]) ++rel;
    int u = wave - A.rowbase[rel];

    const unsigned short* colind = A.colind;
    const float* Pb = A.Pb[rel];
    const float* qv = A.q[rel];
    const float2* sb = A.sb[rel];
    float2 h = A.sa[rel][u];
    int beg = wave ? A.rowptr[wave - 1] : 0;
    int end = A.rowptr[wave];

    bool act = lane < DD;
    int grp4 = lane >> 4, sub4 = lane & 15;
    float ssum = 0.f;
    float4 a4 = make_float4(0.f, 0.f, 0.f, 0.f);

    for (int base = beg; base < end; base += 64) {
        int idx = base + lane;
        bool vld = idx < end;
        int cb = vld ? (int)colind[idx] : 0;
        float evl = 0.f;
        if (vld) {
            float2 sc = sb[cb];
            evl = __expf(0.5f * (fmaxf(h.x + sc.x, 0.f) + fmaxf(h.y + sc.y, 0.f)));
        }
        ssum += evl;
        int nb = min(64, end - base);
        #pragma unroll 2
        for (int t = 0; t < nb; t += 4) {
            int srcl = t + grp4;
            int c = __shfl(cb, srcl);
            float ev = __shfl(evl, srcl);
            const float4* pc = (const float4*)(Pb + (size_t)c * PS);
            float4 v = pc[sub4];
            a4.x = fmaf(ev, v.x, a4.x);
            a4.y = fmaf(ev, v.y, a4.y);
            a4.z = fmaf(ev, v.z, a4.z);
            a4.w = fmaf(ev, v.w, a4.w);
        }
    }
    #pragma unroll
    for (int off = 32; off >= 16; off >>= 1) {
        a4.x += __shfl_xor(a4.x, off);
        a4.y += __shfl_xor(a4.y, off);
        a4.z += __shfl_xor(a4.z, off);
        a4.w += __shfl_xor(a4.w, off);
    }
    #pragma unroll
    for (int off = 32; off; off >>= 1) ssum += __shfl_xor(ssum, off);

    int src = lane >> 2;
    float fx = __shfl(a4.x, src), fy = __shfl(a4.y, src);
    float fz = __shfl(a4.z, src), fw = __shfl(a4.w, src);
    float za = (lane & 1) ? ((lane & 2) ? fw : fy) : ((lane & 2) ? fz : fx);

    float inv = (ssum > 0.f) ? (1.f / ssum) : 0.f;
    float zl = act ? leakyf(za * inv) : 0.f;

    int fcol = act ? ((lane < DK) ? lane : (lane - DK)) : 0;
    int kbase = (act && lane >= DK) ? DK : 0;
    float o = 0.f;
    const float* W = A.W;
    #pragma unroll
    for (int d = 0; d < DK; ++d) {
        float zd = __shfl(zl, kbase + d);
        o = fmaf(zd, W[d * DK + fcol], o);
    }
    float th = act ? tanhf(o) * qv[fcol] : 0.f;
    float t0 = (lane < DK) ? th : 0.f;
    float t1 = th - t0;
    #pragma unroll
    for (int off = 32; off; off >>= 1) { t0 += __shfl_xor(t0, off); t1 += __shfl_xor(t1, off); }
    float m = fmaxf(t0, t1);
    float e0 = __expf(t0 - m), e1 = __expf(t1 - m);
    float rinv = 1.f / (e0 + e1);

    if (act) A.z[rel][(size_t)u * DD + lane] = o;
    if (lane == 0) {
        A.r[rel][(size_t)u * 2 + 0] = e0 * rinv;
        A.r[rel][(size_t)u * 2 + 1] = e1 * rinv;
    }
}

// ---------------- ego ----------------
static __device__ __forceinline__ void l2norm_store(float* dst, const float* acc) {
    #pragma unroll
    for (int k = 0; k < KF; ++k) {
        float nrm = 0.f;
        for (int f = 0; f < DK; ++f) nrm = fmaf(acc[k * DK + f], acc[k * DK + f], nrm);
        float inv = 1.f / fmaxf(sqrtf(nrm), 1e-12f);
        for (int f = 0; f < DK; ++f) dst[k * DK + f] = acc[k * DK + f] * inv;
    }
}

struct EgoArgs { float* P0; float* P1; const float* zz[8]; const float* rr[8]; int n0, n1; };

__global__ void ego_kernel(EgoArgs A) {
    int g = blockIdx.x * blockDim.x + threadIdx.x;
    if (g >= A.n0 + A.n1) return;
    float acc[DD];
    if (g < A.n0) {
        float* Pr = A.P0 + (size_t)g * PS;
        const float* zr = A.zz[0] + (size_t)g * DD;
        float r0 = A.rr[0][(size_t)g * 2], r1 = A.rr[0][(size_t)g * 2 + 1];
        #pragma unroll
        for (int j = 0; j < DD; ++j) acc[j] = fmaf(zr[j], (j < DK ? r0 : r1), Pr[j]);
        l2norm_store(Pr, acc);
    } else {
        int node = g - A.n0;
        float* Pr = A.P1 + (size_t)node * PS;
        #pragma unroll
        for (int j = 0; j < DD; ++j) acc[j] = Pr[j];
        for (int e = 1; e < 8; ++e) {
            const float* zr = A.zz[e] + (size_t)node * DD;
            float r0 = A.rr[e][(size_t)node * 2], r1 = A.rr[e][(size_t)node * 2 + 1];
            #pragma unroll
            for (int j = 0; j < DD; ++j) acc[j] = fmaf(zr[j], (j < DK ? r0 : r1), acc[j]);
        }
        l2norm_store(Pr, acc);
    }
}

// ---------------- output: strided copy P(52) -> out(50) ----------------
__global__ void out_kernel(const float* __restrict__ P0, const float* __restrict__ P1,
                           int n0, int n1, float* __restrict__ out) {
    int g = blockIdx.x * blockDim.x + threadIdx.x;
    if (g >= n0 + n1) return;
    const float* src = (g < n0) ? (P0 + (size_t)g * PS) : (P1 + (size_t)(g - n0) * PS);
    float* dst = out + (size_t)g * DD;
    #pragma unroll
    for (int j = 0; j < DD; ++j) dst[j] = src[j];
}

static inline int cdiv(int a, int b) { return (a + b - 1) / b; }

extern "C" void kernel_launch(void* const* d_in, const int* in_sizes, int n_in,
                              void* d_out, int out_size, void* d_ws, size_t ws_size,
                              hipStream_t stream) {
    const int* edge[8];
    int E[8];
    for (int e = 0; e < 8; ++e) { edge[e] = (const int*)d_in[e]; E[e] = in_sizes[e] / 2; }
    const float* emb[8];
    int nn[8];
    for (int i = 0; i < 8; ++i) { emb[i] = (const float*)d_in[8 + i]; nn[i] = in_sizes[8 + i] / DD; }
    const float* Wtk = (const float*)d_in[16];
    const float* at  = (const float*)d_in[17];
    const float* W   = (const float*)d_in[18];
    const float* q   = (const float*)d_in[19];
    float* out = (float*)d_out;

    static const int aIdx[8] = {0, 1, 1, 1, 1, 1, 1, 1};
    static const int bIdx[8] = {1, 0, 2, 3, 4, 5, 6, 7};
    int rows[8], ncol[8];
    for (int e = 0; e < 8; ++e) { rows[e] = nn[aIdx[e]]; ncol[e] = nn[bIdx[e]]; }
    int rowbase[9];
    rowbase[0] = 0;
    for (int e = 0; e < 8; ++e) rowbase[e + 1] = rowbase[e] + rows[e];
    int totalRows = rowbase[8];
    int ebase[9];
    ebase[0] = 0;
    for (int e = 0; e < 8; ++e) ebase[e + 1] = ebase[e] + E[e];
    int totE = ebase[8];

    // ---- workspace: P(52), z, r, sb, sa, cnt, bsum, colind(u16) ≈ 106 MB ----
    char* w = (char*)d_ws;
    size_t off = 0;
    auto alloc_f  = [&](size_t n) { float*  p = (float*)(w + off);  off += n * 4; return p; };
    auto alloc_f2 = [&](size_t n) { float2* p = (float2*)(w + off); off += n * 8; return p; };
    auto alloc_i  = [&](size_t n) { int*    p = (int*)(w + off);    off += n * 4; return p; };
    float* P[8]; for (int i = 0; i < 8; ++i) P[i] = alloc_f((size_t)nn[i] * PS);
    float* z[8]; for (int e = 0; e < 8; ++e) z[e] = alloc_f((size_t)rows[e] * DD);
    float* r[8]; for (int e = 0; e < 8; ++e) r[e] = alloc_f((size_t)rows[e] * 2);
    float2* sb[8]; for (int e = 0; e < 8; ++e) sb[e] = alloc_f2((size_t)ncol[e]);
    float2* sa[8]; for (int e = 0; e < 8; ++e) sa[e] = alloc_f2((size_t)rows[e]);
    int* cnt = alloc_i((size_t)totalRows);
    int nchunks = cdiv(totalRows, 1024);
    int* bsum = alloc_i((size_t)nchunks);
    unsigned short* colind = (unsigned short*)(w + off);
    off += (size_t)totE * 2;
    (void)ws_size;

    const int B = 256;

    // ---- flat CSR build ----
    hipMemsetAsync(cnt, 0, (size_t)totalRows * 4, stream);
    EdgeArgs EA;
    for (int e = 0; e < 8; ++e) {
        EA.rows[e] = edge[e]; EA.cols[e] = edge[e] + E[e];
        EA.rowbase[e] = rowbase[e];
        EA.ebase[e] = ebase[e];
    }
    EA.ebase[8] = ebase[8];
    EA.cnt = cnt; EA.colind = colind;
    hist_kernel<<<cdiv(totE, B), B, 0, stream>>>(EA);
    scan_part_kernel<<<nchunks, 1024, 0, stream>>>(cnt, totalRows, bsum);
    scan_bsum_kernel<<<1, 1024, 0, stream>>>(bsum, nchunks);
    add_off_kernel<<<nchunks, 1024, 0, stream>>>(cnt, totalRows, bsum);
    scatter_kernel<<<cdiv(totE, B), B, 0, stream>>>(EA);   // leaves cnt[w] = inclusive end

    // ---- fac ----
    FacArgs FA;
    FA.base[0] = 0;
    for (int i = 0; i < 8; ++i) { FA.emb[i] = emb[i]; FA.P[i] = P[i]; FA.base[i + 1] = FA.base[i] + nn[i]; }
    FA.Wtk = Wtk;
    fac_kernel<<<cdiv(FA.base[8], B), B, 0, stream>>>(FA);

    // ---- static sb (rels 2..7) once ----
    SbArgs SBs;
    SBs.base[0] = 0;
    for (int e = 2; e < 8; ++e) {
        SBs.Pb[e - 2] = P[bIdx[e]];
        SBs.at[e - 2] = at + (size_t)e * KF * DD;
        SBs.sb[e - 2] = sb[e];
        SBs.base[e - 1] = SBs.base[e - 2] + ncol[e];
    }
    sb_kernel<<<cdiv(SBs.base[6], B), B, 0, stream>>>(SBs);

    // ---- dynamic scores (sa all rels + sb0/sb1) ----
    ScoreArgs SC;
    SC.P0 = P[0]; SC.P1 = P[1]; SC.at = at;
    for (int e = 0; e < 8; ++e) SC.sa[e] = sa[e];
    SC.sb0 = sb[0]; SC.sb1 = sb[1];
    SC.n0 = nn[0]; SC.n1 = nn[1];
    score01_kernel<<<cdiv(nn[0] + nn[1], B), B, 0, stream>>>(SC);

    // ---- iterations ----
    PhaseArgs PA;
    PA.rowptr = cnt; PA.colind = colind;
    for (int e = 0; e < 8; ++e) {
        PA.Pb[e] = P[bIdx[e]];
        PA.q[e]  = q + (size_t)e * DK;
        PA.sa[e] = sa[e]; PA.sb[e] = sb[e];
        PA.z[e] = z[e]; PA.r[e] = r[e];
        PA.rowbase[e] = rowbase[e];
    }
    PA.rowbase[8] = rowbase[8];
    PA.W = W;
    EgoArgs GA;
    GA.P0 = P[0]; GA.P1 = P[1]; GA.n0 = nn[0]; GA.n1 = nn[1];
    for (int e = 0; e < 8; ++e) { GA.zz[e] = z[e]; GA.rr[e] = r[e]; }

    for (int it = 0; it < ITERS; ++it) {
        phase_kernel<<<cdiv(totalRows, WPB), WPB * 64, 0, stream>>>(PA, totalRows);
        ego_kernel<<<cdiv(nn[0] + nn[1], B), B, 0, stream>>>(GA);
        score01_kernel<<<cdiv(nn[0] + nn[1], B), B, 0, stream>>>(SC);
    }

    // ---- output ----
    out_kernel<<<cdiv(nn[0] + nn[1], B), B, 0, stream>>>(P[0], P[1], nn[0], nn[1], out);
}